// Round 2
// baseline (3567.752 us; speedup 1.0000x reference)
//
#include <hip/hip_runtime.h>

typedef unsigned short u16;
typedef unsigned int u32;

#define W_ 224
#define H_ 128
#define C_ 128
#define NH 8
#define HD 16
#define PREP_STRIDE 4128  // 4*8*128 w-tables + 4*8 scalars

typedef __bf16 bf16x8 __attribute__((ext_vector_type(8)));
typedef float f32x4 __attribute__((ext_vector_type(4)));

__device__ __forceinline__ u16 f2bf(float f) {
  u32 u = __float_as_uint(f);
  return (u16)((u + 0x7FFFu + ((u >> 16) & 1u)) >> 16);
}
__device__ __forceinline__ float bflo(u32 u) { return __uint_as_float(u << 16); }
__device__ __forceinline__ float bfhi(u32 u) { return __uint_as_float(u & 0xFFFF0000u); }

// ---------------------------------------------------------------------------
// Rank-1 PE decomposition prep. pe[d][f] = (d-223)*u[f] exactly, so
// rpe[d] = (d-223)*(W u) + b. Per weight-set s (12 = 6 layers x {self,cross}):
//   walpha[e][f] = 0.25 * sum_c Wq[e16+c][f] * A_k[e16+c]   (A = W u)
//   wbeta        = 0.25 * sum_c Wq[e16+c][f] * b_k[...]
//   wgamma       = 0.25 * sum_c Wk[e16+c][f] * A_q[...]
//   wdelta       = 0.25 * sum_c Wk[e16+c][f] * b_q[...]
// plus bias-side scalars. All fp32 — removes bf16 from the dominant logits.
// ---------------------------------------------------------------------------
__global__ __launch_bounds__(256) void prep_kernel(
    const float* __restrict__ self_Wi, const float* __restrict__ self_bi,
    const float* __restrict__ cross_Wi, const float* __restrict__ cross_bi,
    float* __restrict__ prep) {
  __shared__ float u[128];
  __shared__ float A[256];
  const int s = blockIdx.x, l = s >> 1;
  const float* Wi = (s & 1) ? cross_Wi + (size_t)l * 384 * 128 : self_Wi + (size_t)l * 384 * 128;
  const float* bi = (s & 1) ? cross_bi + l * 384 : self_bi + l * 384;
  const int tid = threadIdx.x;
  if (tid < 128) {
    float ex = (float)(tid & ~1) * (1.f / 128.f);
    u[tid] = expf(-ex * logf(10000.f));
  }
  __syncthreads();
  {
    float a = 0.f;
    const float* wr = Wi + (size_t)tid * 128;
    for (int f = 0; f < 128; ++f) a += wr[f] * u[f];
    A[tid] = a;
  }
  __syncthreads();
  float* out = prep + (size_t)s * PREP_STRIDE;
  for (int t = tid; t < 4096; t += 256) {
    int v = t >> 10, e = (t >> 7) & 7, f = t & 127;
    float acc = 0.f;
#pragma unroll
    for (int c = 0; c < 16; ++c) {
      int qrow = e * 16 + c, krow = 128 + e * 16 + c;
      if (v == 0)      acc += Wi[(size_t)qrow * 128 + f] * A[krow];
      else if (v == 1) acc += Wi[(size_t)qrow * 128 + f] * bi[krow];
      else if (v == 2) acc += Wi[(size_t)krow * 128 + f] * A[qrow];
      else             acc += Wi[(size_t)krow * 128 + f] * bi[qrow];
    }
    out[t] = acc * 0.25f;
  }
  if (tid < 32) {
    int v = tid >> 3, e = tid & 7;
    float acc = 0.f;
#pragma unroll
    for (int c = 0; c < 16; ++c) {
      int qrow = e * 16 + c, krow = 128 + e * 16 + c;
      if (v == 0)      acc += bi[qrow] * A[krow];
      else if (v == 1) acc += bi[qrow] * bi[krow];
      else if (v == 2) acc += bi[krow] * A[qrow];
      else             acc += bi[krow] * bi[qrow];
    }
    out[4096 + tid] = acc * 0.25f;
  }
}

// ---------------------------------------------------------------------------
// Generic 64x64-tile bf16 MFMA GEMM:  out = A[M x 128] * B[N x 128]^T + bias
// mode 0: scatter q(*0.25)/k/v   (self qkv, N=384)
// mode 1: scatter q(*0.25)       (cross q, N=128)
// mode 2: scatter k/v            (cross kv, N=256)
// mode 4: fout[row*128+col] += acc + bias        (out-proj residual)
// mode 5: fout[row*128+col]  = acc + bias        (feat conv)
// ---------------------------------------------------------------------------
__global__ __launch_bounds__(256) void gemm_kernel(
    const u16* __restrict__ A, const u16* __restrict__ B,
    const float* __restrict__ bias, int mode, float* __restrict__ fout,
    u16* __restrict__ out0, u16* __restrict__ out1, u16* __restrict__ out2) {
  __shared__ u16 As[64 * 136];
  __shared__ u16 Bs[64 * 136];
  const int tid = threadIdx.x;
  const int M0 = blockIdx.x * 64, N0 = blockIdx.y * 64;
  const uint4* Ag = (const uint4*)(A + (size_t)M0 * 128);
  const uint4* Bg = (const uint4*)(B + (size_t)N0 * 128);
  for (int t = tid; t < 1024; t += 256) {
    int row = t >> 4, cc = t & 15;
    *(uint4*)&As[row * 136 + cc * 8] = Ag[row * 16 + cc];
  }
  for (int t = tid; t < 1024; t += 256) {
    int row = t >> 4, cc = t & 15;
    *(uint4*)&Bs[row * 136 + cc * 8] = Bg[row * 16 + cc];
  }
  __syncthreads();
  const int wave = tid >> 6, lane = tid & 63;
  const int wm = (wave >> 1) * 32, wn = (wave & 1) * 32;
  const int lr = lane & 15, kq = (lane >> 4) * 8;
  f32x4 acc[2][2] = {};
#pragma unroll
  for (int ks = 0; ks < 4; ++ks) {
    int ko = ks * 32 + kq;
    bf16x8 a0 = *(const bf16x8*)&As[(wm + lr) * 136 + ko];
    bf16x8 a1 = *(const bf16x8*)&As[(wm + 16 + lr) * 136 + ko];
    bf16x8 b0 = *(const bf16x8*)&Bs[(wn + lr) * 136 + ko];
    bf16x8 b1 = *(const bf16x8*)&Bs[(wn + 16 + lr) * 136 + ko];
    acc[0][0] = __builtin_amdgcn_mfma_f32_16x16x32_bf16(a0, b0, acc[0][0], 0, 0, 0);
    acc[0][1] = __builtin_amdgcn_mfma_f32_16x16x32_bf16(a0, b1, acc[0][1], 0, 0, 0);
    acc[1][0] = __builtin_amdgcn_mfma_f32_16x16x32_bf16(a1, b0, acc[1][0], 0, 0, 0);
    acc[1][1] = __builtin_amdgcn_mfma_f32_16x16x32_bf16(a1, b1, acc[1][1], 0, 0, 0);
  }
  const int colq = lane & 15, rowq = (lane >> 4) * 4;
#pragma unroll
  for (int tm = 0; tm < 2; ++tm)
#pragma unroll
    for (int tn = 0; tn < 2; ++tn) {
#pragma unroll
      for (int r = 0; r < 4; ++r) {
        int row = M0 + wm + tm * 16 + rowq + r;
        int col = N0 + wn + tn * 16 + colq;
        float v = acc[tm][tn][r] + bias[col];
        if (mode == 4) {
          fout[(size_t)row * 128 + col] += v;
        } else if (mode == 5) {
          fout[(size_t)row * 128 + col] = v;
        } else {
          int part = (mode == 0) ? (col >> 7) : ((mode == 1) ? 0 : 1 + (col >> 7));
          int cc = col & 127;
          int e = cc >> 4, c = cc & 15;
          int b = row & 127, pos = row >> 7;
          size_t off = ((size_t)(b * NH + e) * W_ + pos) * HD + c;
          if (part == 0)
            out0[off] = f2bf(v * 0.25f);
          else if (part == 1)
            out1[off] = f2bf(v);
          else
            out2[off] = f2bf(v);
        }
      }
    }
}

// ---------------------------------------------------------------------------
// Fused attention per (head e, batch-row b): online softmax over j, PV accum.
// thread = (i, j-half). S[i,j] = q_s[i]·k[j] + (j-i)*(alpha_i+gamma_j)
//                               + beta_i + delta_j   (all /4-scaled already)
// ---------------------------------------------------------------------------
__global__ __launch_bounds__(448, 4) void attn_kernel(
    const u16* __restrict__ qb, const u16* __restrict__ kb,
    const u16* __restrict__ vb, const float* __restrict__ ALPHA,
    const float* __restrict__ BETA, const float* __restrict__ GAMMA,
    const float* __restrict__ DELTA, u16* __restrict__ obuf) {
  __shared__ float Kl[224 * 16];
  __shared__ float Vl[224 * 16];
  __shared__ float Gj[224];
  __shared__ float Dj[224];
  const int e = blockIdx.x, b = blockIdx.y;
  const int tid = threadIdx.x;
  const size_t hb = (size_t)(b * NH + e);

  const u32* kg = (const u32*)(kb + hb * W_ * HD);
  const u32* vg = (const u32*)(vb + hb * W_ * HD);
  for (int t = tid; t < W_ * HD / 2; t += 448) {
    u32 u = kg[t];
    Kl[2 * t] = bflo(u);
    Kl[2 * t + 1] = bfhi(u);
    u = vg[t];
    Vl[2 * t] = bflo(u);
    Vl[2 * t + 1] = bfhi(u);
  }
  if (tid < 224) {
    Gj[tid] = GAMMA[hb * 224 + tid];
    Dj[tid] = DELTA[hb * 224 + tid];
  }
  __syncthreads();

  const int i = tid >> 1, jq = tid & 1;
  const float alpha = ALPHA[hb * 224 + i];
  const float beta = BETA[hb * 224 + i];
  float m = -1e30f, l = 0.f;
  float acc[16];
#pragma unroll
  for (int c = 0; c < 16; ++c) acc[c] = 0.f;

  float qf[16];
  {
    const uint4* qp = (const uint4*)(qb + (hb * W_ + i) * HD);
    uint4 qa = qp[0], qb2 = qp[1];
    qf[0] = bflo(qa.x);  qf[1] = bfhi(qa.x);  qf[2] = bflo(qa.y);  qf[3] = bfhi(qa.y);
    qf[4] = bflo(qa.z);  qf[5] = bfhi(qa.z);  qf[6] = bflo(qa.w);  qf[7] = bfhi(qa.w);
    qf[8] = bflo(qb2.x); qf[9] = bfhi(qb2.x); qf[10] = bflo(qb2.y); qf[11] = bfhi(qb2.y);
    qf[12] = bflo(qb2.z); qf[13] = bfhi(qb2.z); qf[14] = bflo(qb2.w); qf[15] = bfhi(qb2.w);
  }
  const int j0 = jq * 112;
  for (int jj = 0; jj < 112; ++jj) {
    const int j = j0 + jj;
    const float4* kp = (const float4*)&Kl[j * 16];
    float4 ka = kp[0], kb4 = kp[1], kc4 = kp[2], kd4 = kp[3];
    float s0 = qf[0] * ka.x + qf[1] * ka.y + qf[4] * kb4.x + qf[5] * kb4.y;
    float s1 = qf[2] * ka.z + qf[3] * ka.w + qf[6] * kb4.z + qf[7] * kb4.w;
    float s2 = qf[8] * kc4.x + qf[9] * kc4.y + qf[12] * kd4.x + qf[13] * kd4.y;
    float s3 = qf[10] * kc4.z + qf[11] * kc4.w + qf[14] * kd4.z + qf[15] * kd4.w;
    float s = (s0 + s1) + (s2 + s3);
    s += (float)(j - i) * (alpha + Gj[j]) + beta + Dj[j];
    if (s > m) {
      float fs = __expf(m - s);
      l *= fs;
#pragma unroll
      for (int c = 0; c < 16; ++c) acc[c] *= fs;
      m = s;
    }
    float p = __expf(s - m);
    l += p;
    const float4* vp = (const float4*)&Vl[j * 16];
    float4 va = vp[0], vb4 = vp[1], vc4 = vp[2], vd4 = vp[3];
    acc[0] += p * va.x;  acc[1] += p * va.y;  acc[2] += p * va.z;  acc[3] += p * va.w;
    acc[4] += p * vb4.x; acc[5] += p * vb4.y; acc[6] += p * vb4.z; acc[7] += p * vb4.w;
    acc[8] += p * vc4.x; acc[9] += p * vc4.y; acc[10] += p * vc4.z; acc[11] += p * vc4.w;
    acc[12] += p * vd4.x; acc[13] += p * vd4.y; acc[14] += p * vd4.z; acc[15] += p * vd4.w;
  }
  // merge the two j-halves: pair lanes (tid = i*2 + jq) via shfl_xor(.,1)
  float mo = __shfl_xor(m, 1);
  float M2 = fmaxf(m, mo);
  float f = __expf(m - M2), fo = __expf(mo - M2);
  float lo = __shfl_xor(l, 1);
  float L = l * f + lo * fo;
  float inv = 1.f / L;
  u16* op = obuf + ((size_t)i * H_ + b) * C_ + e * HD;
#pragma unroll
  for (int c = 0; c < 16; ++c) {
    float am = acc[c] * f + __shfl_xor(acc[c], 1) * fo;
    if (jq == 0) op[c] = f2bf(am * inv);
  }
}

// ---------------------------------------------------------------------------
// LayerNorm over C=128 (in-place fp32 + bf16 copy) fused with the fp32
// affine-PE table GEMVs: alpha/beta (q-side, wq) and gamma/delta (k-side, wk).
// ---------------------------------------------------------------------------
__global__ __launch_bounds__(256) void ln_kernel(
    float* __restrict__ x, u16* __restrict__ xbf, const float* __restrict__ g,
    const float* __restrict__ b, const float* __restrict__ wq,
    const float* __restrict__ cq, float* __restrict__ outA, float* __restrict__ outB,
    const float* __restrict__ wk, const float* __restrict__ ck,
    float* __restrict__ outG, float* __restrict__ outD) {
  __shared__ float ys[4][128];
  __shared__ float ws[32][129];
  const int tid = threadIdx.x;
  if (wq)
    for (int t = tid; t < 2048; t += 256) ws[t >> 7][t & 127] = wq[t];
  if (wk)
    for (int t = tid; t < 2048; t += 256) ws[16 + (t >> 7)][t & 127] = wk[t];
  const int row = blockIdx.x * 4 + (tid >> 6);
  const int lane = tid & 63;
  float2* xp = (float2*)(x + (size_t)row * 128);
  float2 v = xp[lane];
  float s1 = v.x + v.y, s2 = v.x * v.x + v.y * v.y;
#pragma unroll
  for (int k = 1; k < 64; k <<= 1) {
    s1 += __shfl_xor(s1, k);
    s2 += __shfl_xor(s2, k);
  }
  float mean = s1 * (1.f / 128.f);
  float var = s2 * (1.f / 128.f) - mean * mean;
  float rstd = rsqrtf(var + 1e-5f);
  float2 gg = ((const float2*)g)[lane];
  float2 bb = ((const float2*)b)[lane];
  float y0 = (v.x - mean) * rstd * gg.x + bb.x;
  float y1 = (v.y - mean) * rstd * gg.y + bb.y;
  float2 w2;
  w2.x = y0;
  w2.y = y1;
  xp[lane] = w2;
  ((u32*)xbf)[(size_t)row * 64 + lane] = (u32)f2bf(y0) | ((u32)f2bf(y1) << 16);
  ys[tid >> 6][2 * lane] = y0;
  ys[tid >> 6][2 * lane + 1] = y1;
  __syncthreads();
  if (tid < 128) {
    const int r = tid >> 5, o = tid & 31;
    const int side = o >> 4, oo = o & 15;
    const bool active = side ? (wk != nullptr) : (wq != nullptr);
    if (active) {
      const float* wrow = ws[side * 16 + oo];
      const float* yr = ys[r];
      float a0 = 0.f, a1 = 0.f, a2 = 0.f, a3 = 0.f;
#pragma unroll 4
      for (int f = 0; f < 128; f += 4) {
        a0 += yr[f] * wrow[f];
        a1 += yr[f + 1] * wrow[f + 1];
        a2 += yr[f + 2] * wrow[f + 2];
        a3 += yr[f + 3] * wrow[f + 3];
      }
      float acc = (a0 + a1) + (a2 + a3);
      int p = blockIdx.x * 4 + r;
      int i = p >> 7, bb2 = p & 127;
      int val = oo >> 3, e = oo & 7;
      float c = side ? ck[val * 8 + e] : cq[val * 8 + e];
      float* dst = side ? (val ? outD : outG) : (val ? outB : outA);
      dst[((size_t)(bb2 * 8 + e)) * 224 + i] = acc + c;
    }
  }
}

// Gather x[b][c][h][w] -> bf16 A-matrix rows p = w*128 + h*2 + b, cols c.
__global__ __launch_bounds__(256) void transpose_kernel(const float* __restrict__ x,
                                                        u16* __restrict__ xT) {
  __shared__ float tile[128][57];
  const int wt = blockIdx.x * 56, hi = blockIdx.y, bi = blockIdx.z;
  const int wave = threadIdx.x >> 6, lane = threadIdx.x & 63;
  for (int c = wave; c < 128; c += 4) {
    if (lane < 56)
      tile[c][lane] = x[(((size_t)bi * 128 + c) * 64 + hi) * 224 + wt + lane];
  }
  __syncthreads();
  u32* dst = (u32*)xT;
  for (int w = wave; w < 56; w += 4) {
    int p = (wt + w) * 128 + hi * 2 + bi;
    float a = tile[lane * 2][w], b2 = tile[lane * 2 + 1][w];
    dst[(size_t)p * 64 + lane] = (u32)f2bf(a) | ((u32)f2bf(b2) << 16);
  }
}

// ---------------------------------------------------------------------------
// Final soft-argmax. Recomputes layer-5 cross logits from Q/K (full 128-dot)
// plus head-summed affine-PE tables — no SCORE buffer, no atomics.
// ---------------------------------------------------------------------------
__global__ __launch_bounds__(256) void corresp_kernel(
    const u16* __restrict__ qb, const u16* __restrict__ kb,
    const float* __restrict__ ALPHA, const float* __restrict__ BETA,
    const float* __restrict__ GAMMA, const float* __restrict__ DELTA,
    float* __restrict__ out) {
  __shared__ u32 Ks[224 * 64];
  __shared__ float Gs[224], Ds[224];
  const int b = blockIdx.x, tid = threadIdx.x;
  for (int t = tid; t < 224 * 64; t += 256) {
    int j = t >> 6, w = t & 63, e = w >> 3, cp = w & 7;
    Ks[t] = ((const u32*)kb)[((size_t)(b * 8 + e) * 224 + j) * 8 + cp];
  }
  if (tid < 224) {
    float gs = 0.f, ds = 0.f;
#pragma unroll
    for (int e = 0; e < 8; ++e) {
      gs += GAMMA[((size_t)(b * 8 + e)) * 224 + tid];
      ds += DELTA[((size_t)(b * 8 + e)) * 224 + tid];
    }
    Gs[tid] = gs;
    Ds[tid] = ds;
  }
  __syncthreads();
  if (tid >= 224) return;
  const int i = tid;
  u32 qv[64];
#pragma unroll
  for (int e = 0; e < 8; ++e)
#pragma unroll
    for (int cp = 0; cp < 8; ++cp)
      qv[e * 8 + cp] = ((const u32*)qb)[((size_t)(b * 8 + e) * 224 + i) * 8 + cp];
  float ai = 0.f, bi_ = 0.f;
#pragma unroll
  for (int e = 0; e < 8; ++e) {
    ai += ALPHA[((size_t)(b * 8 + e)) * 224 + i];
    bi_ += BETA[((size_t)(b * 8 + e)) * 224 + i];
  }
  float m = -1e30f, l = 0.f, wj = 0.f;
  for (int j = 0; j < 224; ++j) {
    const u32* kr = &Ks[j * 64];
    float p0 = 0.f, p1 = 0.f, p2 = 0.f, p3 = 0.f;
#pragma unroll 8
    for (int w = 0; w < 64; w += 4) {
      u32 a0 = qv[w], k0 = kr[w];
      u32 a1 = qv[w + 1], k1 = kr[w + 1];
      u32 a2 = qv[w + 2], k2 = kr[w + 2];
      u32 a3 = qv[w + 3], k3 = kr[w + 3];
      p0 += bflo(a0) * bflo(k0) + bfhi(a0) * bfhi(k0);
      p1 += bflo(a1) * bflo(k1) + bfhi(a1) * bfhi(k1);
      p2 += bflo(a2) * bflo(k2) + bfhi(a2) * bfhi(k2);
      p3 += bflo(a3) * bflo(k3) + bfhi(a3) * bfhi(k3);
    }
    float s = (p0 + p1) + (p2 + p3);
    s += (float)(j - i) * (ai + Gs[j]) + bi_ + Ds[j];
    if (s > m) {
      float fs = __expf(m - s);
      l *= fs;
      wj *= fs;
      m = s;
    }
    float p = __expf(s - m);
    l += p;
    wj += p * (float)j;
  }
  out[(size_t)b * 224 + i] = (float)i - wj / l;
}

__global__ __launch_bounds__(256) void cvt_kernel(const float* __restrict__ src,
                                                  u16* __restrict__ dst, int n) {
  int idx = blockIdx.x * 256 + threadIdx.x;
  if (idx < n) dst[idx] = f2bf(src[idx]);
}

extern "C" void kernel_launch(void* const* d_in, const int* in_sizes, int n_in,
                              void* d_out, int out_size, void* d_ws, size_t ws_size,
                              hipStream_t stream) {
  (void)in_sizes; (void)n_in; (void)out_size; (void)ws_size;
  const float* x_l = (const float*)d_in[0];
  const float* x_r = (const float*)d_in[1];
  const float* feat_w = (const float*)d_in[2];
  const float* feat_b = (const float*)d_in[3];
  const float* self_Wi = (const float*)d_in[4];
  const float* self_bi = (const float*)d_in[5];
  const float* self_Wo = (const float*)d_in[6];
  const float* self_bo = (const float*)d_in[7];
  const float* cross_Wi = (const float*)d_in[8];
  const float* cross_bi = (const float*)d_in[9];
  const float* cross_Wo = (const float*)d_in[10];
  const float* cross_bo = (const float*)d_in[11];
  const float* ln_g = (const float*)d_in[12];
  const float* ln_b = (const float*)d_in[13];

  char* ws = (char*)d_ws;
  size_t off = 0;
  auto alloc = [&](size_t bytes) {
    char* p = ws + off;
    off += (bytes + 255) & ~(size_t)255;
    return p;
  };
  float* XL = (float*)alloc((size_t)W_ * H_ * C_ * 4);
  float* XR = (float*)alloc((size_t)W_ * H_ * C_ * 4);
  u16* LNA = (u16*)alloc((size_t)W_ * H_ * C_ * 2);
  u16* LNB = (u16*)alloc((size_t)W_ * H_ * C_ * 2);
  u16* XT = (u16*)alloc((size_t)W_ * H_ * C_ * 2);
  u16* QB = (u16*)alloc((size_t)H_ * NH * W_ * HD * 2);
  u16* KB = (u16*)alloc((size_t)H_ * NH * W_ * HD * 2);
  u16* VB = (u16*)alloc((size_t)H_ * NH * W_ * HD * 2);
  u16* OB = (u16*)alloc((size_t)W_ * H_ * C_ * 2);
  u16* WSWI = (u16*)alloc((size_t)6 * 384 * 128 * 2);
  u16* WSWO = (u16*)alloc((size_t)6 * 128 * 128 * 2);
  u16* WCWI = (u16*)alloc((size_t)6 * 384 * 128 * 2);
  u16* WCWO = (u16*)alloc((size_t)6 * 128 * 128 * 2);
  u16* WFEAT = (u16*)alloc((size_t)128 * 128 * 2);
  float* PREP = (float*)alloc((size_t)12 * PREP_STRIDE * 4);
  float* ALPHA = (float*)alloc((size_t)H_ * NH * W_ * 4);
  float* BETA = (float*)alloc((size_t)H_ * NH * W_ * 4);
  float* GAMMA = (float*)alloc((size_t)H_ * NH * W_ * 4);
  float* DELTA = (float*)alloc((size_t)H_ * NH * W_ * 4);

  cvt_kernel<<<64, 256, 0, stream>>>(feat_w, WFEAT, 16384);
  cvt_kernel<<<1152, 256, 0, stream>>>(self_Wi, WSWI, 294912);
  cvt_kernel<<<384, 256, 0, stream>>>(self_Wo, WSWO, 98304);
  cvt_kernel<<<1152, 256, 0, stream>>>(cross_Wi, WCWI, 294912);
  cvt_kernel<<<384, 256, 0, stream>>>(cross_Wo, WCWO, 98304);
  prep_kernel<<<12, 256, 0, stream>>>(self_Wi, self_bi, cross_Wi, cross_bi, PREP);

  transpose_kernel<<<dim3(4, 64, 2), 256, 0, stream>>>(x_l, XT);
  gemm_kernel<<<dim3(448, 2), 256, 0, stream>>>(XT, WFEAT, feat_b, 5, XL, nullptr, nullptr, nullptr);
  transpose_kernel<<<dim3(4, 64, 2), 256, 0, stream>>>(x_r, XT);
  gemm_kernel<<<dim3(448, 2), 256, 0, stream>>>(XT, WFEAT, feat_b, 5, XR, nullptr, nullptr, nullptr);

  for (int l = 0; l < 6; ++l) {
    const u16* sWi = WSWI + (size_t)l * 384 * 128;
    const u16* sWo = WSWO + (size_t)l * 128 * 128;
    const u16* cWi = WCWI + (size_t)l * 384 * 128;
    const u16* cWo = WCWO + (size_t)l * 128 * 128;
    const float* sbi = self_bi + l * 384;
    const float* sbo = self_bo + l * 128;
    const float* cbi = cross_bi + l * 384;
    const float* cbo = cross_bo + l * 128;
    const float* ps = PREP + (size_t)(l * 2) * PREP_STRIDE;
    const float* pc = PREP + (size_t)(l * 2 + 1) * PREP_STRIDE;

    // --- self attention on xl ---
    ln_kernel<<<7168, 256, 0, stream>>>(XL, LNA, ln_g, ln_b, ps, ps + 4096, ALPHA, BETA,
                                        ps + 2048, ps + 4112, GAMMA, DELTA);
    gemm_kernel<<<dim3(448, 6), 256, 0, stream>>>(LNA, sWi, sbi, 0, nullptr, QB, KB, VB);
    attn_kernel<<<dim3(8, 128), 448, 0, stream>>>(QB, KB, VB, ALPHA, BETA, GAMMA, DELTA, OB);
    gemm_kernel<<<dim3(448, 2), 256, 0, stream>>>(OB, sWo, sbo, 4, XL, nullptr, nullptr, nullptr);

    // --- self attention on xr ---
    ln_kernel<<<7168, 256, 0, stream>>>(XR, LNA, ln_g, ln_b, ps, ps + 4096, ALPHA, BETA,
                                        ps + 2048, ps + 4112, GAMMA, DELTA);
    gemm_kernel<<<dim3(448, 6), 256, 0, stream>>>(LNA, sWi, sbi, 0, nullptr, QB, KB, VB);
    attn_kernel<<<dim3(8, 128), 448, 0, stream>>>(QB, KB, VB, ALPHA, BETA, GAMMA, DELTA, OB);
    gemm_kernel<<<dim3(448, 2), 256, 0, stream>>>(OB, sWo, sbo, 4, XR, nullptr, nullptr, nullptr);

    // --- cross attention: q from LN(xr), k/v from LN(xl); xl += out ---
    ln_kernel<<<7168, 256, 0, stream>>>(XL, LNA, ln_g, ln_b, nullptr, nullptr, nullptr, nullptr,
                                        pc + 2048, pc + 4112, GAMMA, DELTA);
    ln_kernel<<<7168, 256, 0, stream>>>(XR, LNB, ln_g, ln_b, pc, pc + 4096, ALPHA, BETA,
                                        nullptr, nullptr, nullptr, nullptr);
    gemm_kernel<<<dim3(448, 2), 256, 0, stream>>>(LNB, cWi, cbi, 1, nullptr, QB, nullptr, nullptr);
    gemm_kernel<<<dim3(448, 4), 256, 0, stream>>>(LNA, cWi + 128 * 128, cbi + 128, 2, nullptr,
                                                  nullptr, KB, VB);
    if (l < 5) {
      attn_kernel<<<dim3(8, 128), 448, 0, stream>>>(QB, KB, VB, ALPHA, BETA, GAMMA, DELTA, OB);
      gemm_kernel<<<dim3(448, 2), 256, 0, stream>>>(OB, cWo, cbo, 4, XL, nullptr, nullptr, nullptr);
    }
    // l == 5: attention output / xl update are dead; corresp reads QB/KB + tables.
  }
  corresp_kernel<<<128, 256, 0, stream>>>(QB, KB, ALPHA, BETA, GAMMA, DELTA, (float*)d_out);
}

// Round 3
// 3319.415 us; speedup vs baseline: 1.0748x; 1.0748x over previous
//
#include <hip/hip_runtime.h>

typedef unsigned short u16;
typedef unsigned int u32;

#define W_ 224
#define H_ 128
#define C_ 128
#define NH 8
#define HD 16
#define PREP_STRIDE 4128  // 4*8*128 w-tables + 4*8 scalars

typedef __bf16 bf16x8 __attribute__((ext_vector_type(8)));
typedef float f32x4 __attribute__((ext_vector_type(4)));

__device__ __forceinline__ u16 f2bf(float f) {
  u32 u = __float_as_uint(f);
  return (u16)((u + 0x7FFFu + ((u >> 16) & 1u)) >> 16);
}
__device__ __forceinline__ float bflo(u32 u) { return __uint_as_float(u << 16); }
__device__ __forceinline__ float bfhi(u32 u) { return __uint_as_float(u & 0xFFFF0000u); }

// ---------------------------------------------------------------------------
// Rank-1 PE decomposition prep (see R1 notes): rpe[d] = (d-223)*(W u) + b,
// collapsed to per-row affine tables, all fp32.
// ---------------------------------------------------------------------------
__global__ __launch_bounds__(256) void prep_kernel(
    const float* __restrict__ self_Wi, const float* __restrict__ self_bi,
    const float* __restrict__ cross_Wi, const float* __restrict__ cross_bi,
    float* __restrict__ prep) {
  __shared__ float u[128];
  __shared__ float A[256];
  const int s = blockIdx.x, l = s >> 1;
  const float* Wi = (s & 1) ? cross_Wi + (size_t)l * 384 * 128 : self_Wi + (size_t)l * 384 * 128;
  const float* bi = (s & 1) ? cross_bi + l * 384 : self_bi + l * 384;
  const int tid = threadIdx.x;
  if (tid < 128) {
    float ex = (float)(tid & ~1) * (1.f / 128.f);
    u[tid] = expf(-ex * logf(10000.f));
  }
  __syncthreads();
  {
    float a = 0.f;
    const float* wr = Wi + (size_t)tid * 128;
    for (int f = 0; f < 128; ++f) a += wr[f] * u[f];
    A[tid] = a;
  }
  __syncthreads();
  float* out = prep + (size_t)s * PREP_STRIDE;
  for (int t = tid; t < 4096; t += 256) {
    int v = t >> 10, e = (t >> 7) & 7, f = t & 127;
    float acc = 0.f;
#pragma unroll
    for (int c = 0; c < 16; ++c) {
      int qrow = e * 16 + c, krow = 128 + e * 16 + c;
      if (v == 0)      acc += Wi[(size_t)qrow * 128 + f] * A[krow];
      else if (v == 1) acc += Wi[(size_t)qrow * 128 + f] * bi[krow];
      else if (v == 2) acc += Wi[(size_t)krow * 128 + f] * A[qrow];
      else             acc += Wi[(size_t)krow * 128 + f] * bi[qrow];
    }
    out[t] = acc * 0.25f;
  }
  if (tid < 32) {
    int v = tid >> 3, e = tid & 7;
    float acc = 0.f;
#pragma unroll
    for (int c = 0; c < 16; ++c) {
      int qrow = e * 16 + c, krow = 128 + e * 16 + c;
      if (v == 0)      acc += bi[qrow] * A[krow];
      else if (v == 1) acc += bi[qrow] * bi[krow];
      else if (v == 2) acc += bi[krow] * A[qrow];
      else             acc += bi[krow] * bi[qrow];
    }
    out[4096 + tid] = acc * 0.25f;
  }
}

// ---------------------------------------------------------------------------
// Generic 64x64-tile bf16 MFMA GEMM:  out = A[M x 128] * B[N x 128]^T + bias
// ---------------------------------------------------------------------------
__global__ __launch_bounds__(256) void gemm_kernel(
    const u16* __restrict__ A, const u16* __restrict__ B,
    const float* __restrict__ bias, int mode, float* __restrict__ fout,
    u16* __restrict__ out0, u16* __restrict__ out1, u16* __restrict__ out2) {
  __shared__ u16 As[64 * 136];
  __shared__ u16 Bs[64 * 136];
  const int tid = threadIdx.x;
  const int M0 = blockIdx.x * 64, N0 = blockIdx.y * 64;
  const uint4* Ag = (const uint4*)(A + (size_t)M0 * 128);
  const uint4* Bg = (const uint4*)(B + (size_t)N0 * 128);
  for (int t = tid; t < 1024; t += 256) {
    int row = t >> 4, cc = t & 15;
    *(uint4*)&As[row * 136 + cc * 8] = Ag[row * 16 + cc];
  }
  for (int t = tid; t < 1024; t += 256) {
    int row = t >> 4, cc = t & 15;
    *(uint4*)&Bs[row * 136 + cc * 8] = Bg[row * 16 + cc];
  }
  __syncthreads();
  const int wave = tid >> 6, lane = tid & 63;
  const int wm = (wave >> 1) * 32, wn = (wave & 1) * 32;
  const int lr = lane & 15, kq = (lane >> 4) * 8;
  f32x4 acc[2][2] = {};
#pragma unroll
  for (int ks = 0; ks < 4; ++ks) {
    int ko = ks * 32 + kq;
    bf16x8 a0 = *(const bf16x8*)&As[(wm + lr) * 136 + ko];
    bf16x8 a1 = *(const bf16x8*)&As[(wm + 16 + lr) * 136 + ko];
    bf16x8 b0 = *(const bf16x8*)&Bs[(wn + lr) * 136 + ko];
    bf16x8 b1 = *(const bf16x8*)&Bs[(wn + 16 + lr) * 136 + ko];
    acc[0][0] = __builtin_amdgcn_mfma_f32_16x16x32_bf16(a0, b0, acc[0][0], 0, 0, 0);
    acc[0][1] = __builtin_amdgcn_mfma_f32_16x16x32_bf16(a0, b1, acc[0][1], 0, 0, 0);
    acc[1][0] = __builtin_amdgcn_mfma_f32_16x16x32_bf16(a1, b0, acc[1][0], 0, 0, 0);
    acc[1][1] = __builtin_amdgcn_mfma_f32_16x16x32_bf16(a1, b1, acc[1][1], 0, 0, 0);
  }
  const int colq = lane & 15, rowq = (lane >> 4) * 4;
#pragma unroll
  for (int tm = 0; tm < 2; ++tm)
#pragma unroll
    for (int tn = 0; tn < 2; ++tn) {
#pragma unroll
      for (int r = 0; r < 4; ++r) {
        int row = M0 + wm + tm * 16 + rowq + r;
        int col = N0 + wn + tn * 16 + colq;
        float v = acc[tm][tn][r] + bias[col];
        if (mode == 4) {
          fout[(size_t)row * 128 + col] += v;
        } else if (mode == 5) {
          fout[(size_t)row * 128 + col] = v;
        } else {
          int part = (mode == 0) ? (col >> 7) : ((mode == 1) ? 0 : 1 + (col >> 7));
          int cc = col & 127;
          int e = cc >> 4, c = cc & 15;
          int b = row & 127, pos = row >> 7;
          size_t off = ((size_t)(b * NH + e) * W_ + pos) * HD + c;
          if (part == 0)
            out0[off] = f2bf(v * 0.25f);
          else if (part == 1)
            out1[off] = f2bf(v);
          else
            out2[off] = f2bf(v);
        }
      }
    }
}

// ---------------------------------------------------------------------------
// Fused attention per (head e, batch-row b).
// Thread = (ii in [0,56), jq in [0,8)); owns i in {ii,+56,+112,+168} (TI=4,
// amortizes each K/V LDS read over 4 rows) and j-slice [jq*28, jq*28+28).
// Branch-free softmax: m-hat = max_j(|q||k_j| + pe) upper bound (logit norms
// are <<1 here, so overshoot is tiny and cannot underflow), then a single
// exp-accumulate pass. 8-way shfl-xor butterfly merges the j-slices.
// ---------------------------------------------------------------------------
__global__ __launch_bounds__(448, 1) void attn_kernel(
    const u16* __restrict__ qb, const u16* __restrict__ kb,
    const u16* __restrict__ vb, const float* __restrict__ ALPHA,
    const float* __restrict__ BETA, const float* __restrict__ GAMMA,
    const float* __restrict__ DELTA, u16* __restrict__ obuf) {
  __shared__ __align__(16) float Kf[224 * 20];  // stride 20 floats (80B, 16B-aligned)
  __shared__ __align__(16) float Vf[224 * 20];
  __shared__ float kn[224];
  __shared__ float Gj[224];
  __shared__ float Dj[224];
  const int e = blockIdx.x, b = blockIdx.y;
  const size_t hb = (size_t)(b * NH + e);
  const int tid = threadIdx.x;

  // --- stage K/V rows (unpack bf16 -> f32), compute |k_j| ---
  {
    const int r = (tid < 224) ? tid : tid - 224;
    const uint4* src = (const uint4*)((tid < 224 ? kb : vb) + hb * W_ * HD);
    uint4 a = src[2 * r], b2 = src[2 * r + 1];
    float f0 = bflo(a.x), f1 = bfhi(a.x), f2 = bflo(a.y), f3 = bfhi(a.y);
    float f4 = bflo(a.z), f5 = bfhi(a.z), f6 = bflo(a.w), f7 = bfhi(a.w);
    float f8 = bflo(b2.x), f9 = bfhi(b2.x), f10 = bflo(b2.y), f11 = bfhi(b2.y);
    float f12 = bflo(b2.z), f13 = bfhi(b2.z), f14 = bflo(b2.w), f15 = bfhi(b2.w);
    float* dst = (tid < 224 ? Kf : Vf) + r * 20;
    *(float4*)&dst[0] = make_float4(f0, f1, f2, f3);
    *(float4*)&dst[4] = make_float4(f4, f5, f6, f7);
    *(float4*)&dst[8] = make_float4(f8, f9, f10, f11);
    *(float4*)&dst[12] = make_float4(f12, f13, f14, f15);
    if (tid < 224) {
      float ss = f0 * f0 + f1 * f1 + f2 * f2 + f3 * f3 + f4 * f4 + f5 * f5 + f6 * f6 +
                 f7 * f7 + f8 * f8 + f9 * f9 + f10 * f10 + f11 * f11 + f12 * f12 +
                 f13 * f13 + f14 * f14 + f15 * f15;
      kn[r] = sqrtf(ss);
      Gj[r] = GAMMA[hb * 224 + r];
      Dj[r] = DELTA[hb * 224 + r];
    }
  }
  __syncthreads();

  const int ii = tid >> 3, jq = tid & 7;
  int iv[4];
  float qf[4][16], qn[4], al[4], be[4];
#pragma unroll
  for (int t = 0; t < 4; ++t) {
    const int i = ii + 56 * t;
    iv[t] = i;
    const uint4* qp = (const uint4*)(qb + (hb * W_ + i) * HD);
    uint4 qa = qp[0], qb2 = qp[1];
    qf[t][0] = bflo(qa.x);  qf[t][1] = bfhi(qa.x);  qf[t][2] = bflo(qa.y);  qf[t][3] = bfhi(qa.y);
    qf[t][4] = bflo(qa.z);  qf[t][5] = bfhi(qa.z);  qf[t][6] = bflo(qa.w);  qf[t][7] = bfhi(qa.w);
    qf[t][8] = bflo(qb2.x); qf[t][9] = bfhi(qb2.x); qf[t][10] = bflo(qb2.y); qf[t][11] = bfhi(qb2.y);
    qf[t][12] = bflo(qb2.z); qf[t][13] = bfhi(qb2.z); qf[t][14] = bflo(qb2.w); qf[t][15] = bfhi(qb2.w);
    float ss = 0.f;
#pragma unroll
    for (int c = 0; c < 16; ++c) ss += qf[t][c] * qf[t][c];
    qn[t] = sqrtf(ss);
    al[t] = ALPHA[hb * 224 + i];
    be[t] = BETA[hb * 224 + i];
  }

  // --- prepass: per-row upper bound on the max logit in this j-slice ---
  float mh[4] = {-1e30f, -1e30f, -1e30f, -1e30f};
  for (int jj = 0; jj < 28; ++jj) {
    const int j = jq * 28 + jj;
    const float knj = kn[j], g = Gj[j], d = Dj[j];
#pragma unroll
    for (int t = 0; t < 4; ++t) {
      float pe = (float)(j - iv[t]) * (al[t] + g) + be[t] + d;
      mh[t] = fmaxf(mh[t], qn[t] * knj + pe);
    }
  }

  // --- main pass: branch-free exp-accumulate ---
  float l[4] = {0.f, 0.f, 0.f, 0.f};
  float acc[4][16] = {};
  for (int jj = 0; jj < 28; ++jj) {
    int jo = jj + jq;              // bank-stagger so 8 slices hit disjoint banks
    if (jo >= 28) jo -= 28;
    const int j = jq * 28 + jo;
    const float4 k0 = *(const float4*)&Kf[j * 20];
    const float4 k1 = *(const float4*)&Kf[j * 20 + 4];
    const float4 k2 = *(const float4*)&Kf[j * 20 + 8];
    const float4 k3 = *(const float4*)&Kf[j * 20 + 12];
    const float4 v0 = *(const float4*)&Vf[j * 20];
    const float4 v1 = *(const float4*)&Vf[j * 20 + 4];
    const float4 v2 = *(const float4*)&Vf[j * 20 + 8];
    const float4 v3 = *(const float4*)&Vf[j * 20 + 12];
    const float g = Gj[j], d = Dj[j];
    const float jf = (float)j;
#pragma unroll
    for (int t = 0; t < 4; ++t) {
      float s0 = qf[t][0] * k0.x + qf[t][1] * k0.y + qf[t][4] * k1.x + qf[t][5] * k1.y;
      float s1 = qf[t][2] * k0.z + qf[t][3] * k0.w + qf[t][6] * k1.z + qf[t][7] * k1.w;
      float s2 = qf[t][8] * k2.x + qf[t][9] * k2.y + qf[t][12] * k3.x + qf[t][13] * k3.y;
      float s3 = qf[t][10] * k2.z + qf[t][11] * k2.w + qf[t][14] * k3.z + qf[t][15] * k3.w;
      float s = (s0 + s1) + (s2 + s3);
      s += (jf - (float)iv[t]) * (al[t] + g) + be[t] + d;
      float p = __expf(s - mh[t]);
      l[t] += p;
      acc[t][0] += p * v0.x;  acc[t][1] += p * v0.y;  acc[t][2] += p * v0.z;  acc[t][3] += p * v0.w;
      acc[t][4] += p * v1.x;  acc[t][5] += p * v1.y;  acc[t][6] += p * v1.z;  acc[t][7] += p * v1.w;
      acc[t][8] += p * v2.x;  acc[t][9] += p * v2.y;  acc[t][10] += p * v2.z; acc[t][11] += p * v2.w;
      acc[t][12] += p * v3.x; acc[t][13] += p * v3.y; acc[t][14] += p * v3.z; acc[t][15] += p * v3.w;
    }
  }

  // --- merge the 8 j-slices (lanes ii*8+jq: partners within the wave) ---
#pragma unroll
  for (int r = 1; r <= 4; r <<= 1) {
#pragma unroll
    for (int t = 0; t < 4; ++t) {
      float mo = __shfl_xor(mh[t], r);
      float m2 = fmaxf(mh[t], mo);
      float fa = __expf(mh[t] - m2), fb = __expf(mo - m2);
      l[t] = l[t] * fa + __shfl_xor(l[t], r) * fb;
#pragma unroll
      for (int c = 0; c < 16; ++c)
        acc[t][c] = acc[t][c] * fa + __shfl_xor(acc[t][c], r) * fb;
      mh[t] = m2;
    }
  }
  if (jq == 0) {
#pragma unroll
    for (int t = 0; t < 4; ++t) {
      const float inv = 1.f / fmaxf(l[t], 1e-30f);
      u32* op = (u32*)(obuf + ((size_t)iv[t] * H_ + b) * C_ + e * HD);
#pragma unroll
      for (int c = 0; c < 8; ++c)
        op[c] = (u32)f2bf(acc[t][2 * c] * inv) | ((u32)f2bf(acc[t][2 * c + 1] * inv) << 16);
    }
  }
}

// ---------------------------------------------------------------------------
// LayerNorm over C=128 fused with the fp32 affine-PE table GEMVs.
// ---------------------------------------------------------------------------
__global__ __launch_bounds__(256) void ln_kernel(
    float* __restrict__ x, u16* __restrict__ xbf, const float* __restrict__ g,
    const float* __restrict__ b, const float* __restrict__ wq,
    const float* __restrict__ cq, float* __restrict__ outA, float* __restrict__ outB,
    const float* __restrict__ wk, const float* __restrict__ ck,
    float* __restrict__ outG, float* __restrict__ outD) {
  __shared__ float ys[4][128];
  __shared__ float ws[32][129];
  const int tid = threadIdx.x;
  if (wq)
    for (int t = tid; t < 2048; t += 256) ws[t >> 7][t & 127] = wq[t];
  if (wk)
    for (int t = tid; t < 2048; t += 256) ws[16 + (t >> 7)][t & 127] = wk[t];
  const int row = blockIdx.x * 4 + (tid >> 6);
  const int lane = tid & 63;
  float2* xp = (float2*)(x + (size_t)row * 128);
  float2 v = xp[lane];
  float s1 = v.x + v.y, s2 = v.x * v.x + v.y * v.y;
#pragma unroll
  for (int k = 1; k < 64; k <<= 1) {
    s1 += __shfl_xor(s1, k);
    s2 += __shfl_xor(s2, k);
  }
  float mean = s1 * (1.f / 128.f);
  float var = s2 * (1.f / 128.f) - mean * mean;
  float rstd = rsqrtf(var + 1e-5f);
  float2 gg = ((const float2*)g)[lane];
  float2 bb = ((const float2*)b)[lane];
  float y0 = (v.x - mean) * rstd * gg.x + bb.x;
  float y1 = (v.y - mean) * rstd * gg.y + bb.y;
  float2 w2;
  w2.x = y0;
  w2.y = y1;
  xp[lane] = w2;
  ((u32*)xbf)[(size_t)row * 64 + lane] = (u32)f2bf(y0) | ((u32)f2bf(y1) << 16);
  ys[tid >> 6][2 * lane] = y0;
  ys[tid >> 6][2 * lane + 1] = y1;
  __syncthreads();
  if (tid < 128) {
    const int r = tid >> 5, o = tid & 31;
    const int side = o >> 4, oo = o & 15;
    const bool active = side ? (wk != nullptr) : (wq != nullptr);
    if (active) {
      const float* wrow = ws[side * 16 + oo];
      const float* yr = ys[r];
      float a0 = 0.f, a1 = 0.f, a2 = 0.f, a3 = 0.f;
#pragma unroll 4
      for (int f = 0; f < 128; f += 4) {
        a0 += yr[f] * wrow[f];
        a1 += yr[f + 1] * wrow[f + 1];
        a2 += yr[f + 2] * wrow[f + 2];
        a3 += yr[f + 3] * wrow[f + 3];
      }
      float acc = (a0 + a1) + (a2 + a3);
      int p = blockIdx.x * 4 + r;
      int i = p >> 7, bb2 = p & 127;
      int val = oo >> 3, e = oo & 7;
      float c = side ? ck[val * 8 + e] : cq[val * 8 + e];
      float* dst = side ? (val ? outD : outG) : (val ? outB : outA);
      dst[((size_t)(bb2 * 8 + e)) * 224 + i] = acc + c;
    }
  }
}

// Gather x[b][c][h][w] -> bf16 A-matrix rows p = w*128 + h*2 + b, cols c.
__global__ __launch_bounds__(256) void transpose_kernel(const float* __restrict__ x,
                                                        u16* __restrict__ xT) {
  __shared__ float tile[128][57];
  const int wt = blockIdx.x * 56, hi = blockIdx.y, bi = blockIdx.z;
  const int wave = threadIdx.x >> 6, lane = threadIdx.x & 63;
  for (int c = wave; c < 128; c += 4) {
    if (lane < 56)
      tile[c][lane] = x[(((size_t)bi * 128 + c) * 64 + hi) * 224 + wt + lane];
  }
  __syncthreads();
  u32* dst = (u32*)xT;
  for (int w = wave; w < 56; w += 4) {
    int p = (wt + w) * 128 + hi * 2 + bi;
    float a = tile[lane * 2][w], b2 = tile[lane * 2 + 1][w];
    dst[(size_t)p * 64 + lane] = (u32)f2bf(a) | ((u32)f2bf(b2) << 16);
  }
}

// ---------------------------------------------------------------------------
// Final soft-argmax over recomputed layer-5 cross logits.
// Grid (b, i-half); thread = (ii in [0,112), jq in [0,4)); shfl merge.
// ---------------------------------------------------------------------------
__global__ __launch_bounds__(448, 1) void corresp_kernel(
    const u16* __restrict__ qb, const u16* __restrict__ kb,
    const float* __restrict__ ALPHA, const float* __restrict__ BETA,
    const float* __restrict__ GAMMA, const float* __restrict__ DELTA,
    float* __restrict__ out) {
  __shared__ __align__(16) u32 Ks[224 * 68];  // stride 68 dwords (272B, 16B-aligned)
  __shared__ float Gs[224], Ds[224];
  const int b = blockIdx.x, tid = threadIdx.x;
  const u32* kg = (const u32*)kb;
  for (int t = tid; t < 224 * 64; t += 448) {
    int row = t >> 6, col = t & 63;
    Ks[row * 68 + col] = kg[((size_t)(b * 8 + (col >> 3)) * 224 + row) * 8 + (col & 7)];
  }
  if (tid < 224) {
    float gs = 0.f, ds = 0.f;
#pragma unroll
    for (int e = 0; e < 8; ++e) {
      gs += GAMMA[((size_t)(b * 8 + e)) * 224 + tid];
      ds += DELTA[((size_t)(b * 8 + e)) * 224 + tid];
    }
    Gs[tid] = gs;
    Ds[tid] = ds;
  }
  __syncthreads();
  const int ii = tid >> 2, jq = tid & 3;
  const int i = blockIdx.y * 112 + ii;
  float qf[128];
  const u32* qg = (const u32*)qb;
#pragma unroll
  for (int uu = 0; uu < 64; ++uu) {
    u32 qv = qg[((size_t)(b * 8 + (uu >> 3)) * 224 + i) * 8 + (uu & 7)];
    qf[2 * uu] = bflo(qv);
    qf[2 * uu + 1] = bfhi(qv);
  }
  float ai = 0.f, bi_ = 0.f;
#pragma unroll
  for (int e = 0; e < 8; ++e) {
    ai += ALPHA[((size_t)(b * 8 + e)) * 224 + i];
    bi_ += BETA[((size_t)(b * 8 + e)) * 224 + i];
  }
  float m = -1e30f, l = 0.f, wj = 0.f;
  for (int jj = 0; jj < 56; ++jj) {
    int jo = jj + jq * 14;  // bank-stagger across the 4 slices
    if (jo >= 56) jo -= 56;
    const int j = jq * 56 + jo;
    const u32* kr = &Ks[j * 68];
    float p0 = 0.f, p1 = 0.f, p2 = 0.f, p3 = 0.f;
#pragma unroll
    for (int w = 0; w < 16; ++w) {
      uint4 kk = *(const uint4*)&kr[w * 4];
      p0 += qf[w * 8 + 0] * bflo(kk.x) + qf[w * 8 + 1] * bfhi(kk.x);
      p1 += qf[w * 8 + 2] * bflo(kk.y) + qf[w * 8 + 3] * bfhi(kk.y);
      p2 += qf[w * 8 + 4] * bflo(kk.z) + qf[w * 8 + 5] * bfhi(kk.z);
      p3 += qf[w * 8 + 6] * bflo(kk.w) + qf[w * 8 + 7] * bfhi(kk.w);
    }
    float s = (p0 + p1) + (p2 + p3);
    s += (float)(j - i) * (ai + Gs[j]) + bi_ + Ds[j];
    if (s > m) {
      float fs = __expf(m - s);
      l *= fs;
      wj *= fs;
      m = s;
    }
    float p = __expf(s - m);
    l += p;
    wj += p * (float)j;
  }
#pragma unroll
  for (int r = 1; r <= 2; r <<= 1) {
    float mo = __shfl_xor(m, r);
    float m2 = fmaxf(m, mo);
    float fa = __expf(m - m2), fb = __expf(mo - m2);
    l = l * fa + __shfl_xor(l, r) * fb;
    wj = wj * fa + __shfl_xor(wj, r) * fb;
    m = m2;
  }
  if (jq == 0) out[(size_t)b * 224 + i] = (float)i - wj / fmaxf(l, 1e-30f);
}

__global__ __launch_bounds__(256) void cvt_kernel(const float* __restrict__ src,
                                                  u16* __restrict__ dst, int n) {
  int idx = blockIdx.x * 256 + threadIdx.x;
  if (idx < n) dst[idx] = f2bf(src[idx]);
}

extern "C" void kernel_launch(void* const* d_in, const int* in_sizes, int n_in,
                              void* d_out, int out_size, void* d_ws, size_t ws_size,
                              hipStream_t stream) {
  (void)in_sizes; (void)n_in; (void)out_size; (void)ws_size;
  const float* x_l = (const float*)d_in[0];
  const float* x_r = (const float*)d_in[1];
  const float* feat_w = (const float*)d_in[2];
  const float* feat_b = (const float*)d_in[3];
  const float* self_Wi = (const float*)d_in[4];
  const float* self_bi = (const float*)d_in[5];
  const float* self_Wo = (const float*)d_in[6];
  const float* self_bo = (const float*)d_in[7];
  const float* cross_Wi = (const float*)d_in[8];
  const float* cross_bi = (const float*)d_in[9];
  const float* cross_Wo = (const float*)d_in[10];
  const float* cross_bo = (const float*)d_in[11];
  const float* ln_g = (const float*)d_in[12];
  const float* ln_b = (const float*)d_in[13];

  char* ws = (char*)d_ws;
  size_t off = 0;
  auto alloc = [&](size_t bytes) {
    char* p = ws + off;
    off += (bytes + 255) & ~(size_t)255;
    return p;
  };
  float* XL = (float*)alloc((size_t)W_ * H_ * C_ * 4);
  float* XR = (float*)alloc((size_t)W_ * H_ * C_ * 4);
  u16* LNA = (u16*)alloc((size_t)W_ * H_ * C_ * 2);
  u16* LNB = (u16*)alloc((size_t)W_ * H_ * C_ * 2);
  u16* XT = (u16*)alloc((size_t)W_ * H_ * C_ * 2);
  u16* QB = (u16*)alloc((size_t)H_ * NH * W_ * HD * 2);
  u16* KB = (u16*)alloc((size_t)H_ * NH * W_ * HD * 2);
  u16* VB = (u16*)alloc((size_t)H_ * NH * W_ * HD * 2);
  u16* OB = (u16*)alloc((size_t)W_ * H_ * C_ * 2);
  u16* WSWI = (u16*)alloc((size_t)6 * 384 * 128 * 2);
  u16* WSWO = (u16*)alloc((size_t)6 * 128 * 128 * 2);
  u16* WCWI = (u16*)alloc((size_t)6 * 384 * 128 * 2);
  u16* WCWO = (u16*)alloc((size_t)6 * 128 * 128 * 2);
  u16* WFEAT = (u16*)alloc((size_t)128 * 128 * 2);
  float* PREP = (float*)alloc((size_t)12 * PREP_STRIDE * 4);
  float* ALPHA = (float*)alloc((size_t)H_ * NH * W_ * 4);
  float* BETA = (float*)alloc((size_t)H_ * NH * W_ * 4);
  float* GAMMA = (float*)alloc((size_t)H_ * NH * W_ * 4);
  float* DELTA = (float*)alloc((size_t)H_ * NH * W_ * 4);

  cvt_kernel<<<64, 256, 0, stream>>>(feat_w, WFEAT, 16384);
  cvt_kernel<<<1152, 256, 0, stream>>>(self_Wi, WSWI, 294912);
  cvt_kernel<<<384, 256, 0, stream>>>(self_Wo, WSWO, 98304);
  cvt_kernel<<<1152, 256, 0, stream>>>(cross_Wi, WCWI, 294912);
  cvt_kernel<<<384, 256, 0, stream>>>(cross_Wo, WCWO, 98304);
  prep_kernel<<<12, 256, 0, stream>>>(self_Wi, self_bi, cross_Wi, cross_bi, PREP);

  transpose_kernel<<<dim3(4, 64, 2), 256, 0, stream>>>(x_l, XT);
  gemm_kernel<<<dim3(448, 2), 256, 0, stream>>>(XT, WFEAT, feat_b, 5, XL, nullptr, nullptr, nullptr);
  transpose_kernel<<<dim3(4, 64, 2), 256, 0, stream>>>(x_r, XT);
  gemm_kernel<<<dim3(448, 2), 256, 0, stream>>>(XT, WFEAT, feat_b, 5, XR, nullptr, nullptr, nullptr);

  for (int l = 0; l < 6; ++l) {
    const u16* sWi = WSWI + (size_t)l * 384 * 128;
    const u16* sWo = WSWO + (size_t)l * 128 * 128;
    const u16* cWi = WCWI + (size_t)l * 384 * 128;
    const u16* cWo = WCWO + (size_t)l * 128 * 128;
    const float* sbi = self_bi + l * 384;
    const float* sbo = self_bo + l * 128;
    const float* cbi = cross_bi + l * 384;
    const float* cbo = cross_bo + l * 128;
    const float* ps = PREP + (size_t)(l * 2) * PREP_STRIDE;
    const float* pc = PREP + (size_t)(l * 2 + 1) * PREP_STRIDE;

    // --- self attention on xl ---
    ln_kernel<<<7168, 256, 0, stream>>>(XL, LNA, ln_g, ln_b, ps, ps + 4096, ALPHA, BETA,
                                        ps + 2048, ps + 4112, GAMMA, DELTA);
    gemm_kernel<<<dim3(448, 6), 256, 0, stream>>>(LNA, sWi, sbi, 0, nullptr, QB, KB, VB);
    attn_kernel<<<dim3(8, 128), 448, 0, stream>>>(QB, KB, VB, ALPHA, BETA, GAMMA, DELTA, OB);
    gemm_kernel<<<dim3(448, 2), 256, 0, stream>>>(OB, sWo, sbo, 4, XL, nullptr, nullptr, nullptr);

    // --- self attention on xr ---
    ln_kernel<<<7168, 256, 0, stream>>>(XR, LNA, ln_g, ln_b, ps, ps + 4096, ALPHA, BETA,
                                        ps + 2048, ps + 4112, GAMMA, DELTA);
    gemm_kernel<<<dim3(448, 6), 256, 0, stream>>>(LNA, sWi, sbi, 0, nullptr, QB, KB, VB);
    attn_kernel<<<dim3(8, 128), 448, 0, stream>>>(QB, KB, VB, ALPHA, BETA, GAMMA, DELTA, OB);
    gemm_kernel<<<dim3(448, 2), 256, 0, stream>>>(OB, sWo, sbo, 4, XR, nullptr, nullptr, nullptr);

    // --- cross attention: q from LN(xr), k/v from LN(xl); xl += out ---
    ln_kernel<<<7168, 256, 0, stream>>>(XL, LNA, ln_g, ln_b, nullptr, nullptr, nullptr, nullptr,
                                        pc + 2048, pc + 4112, GAMMA, DELTA);
    ln_kernel<<<7168, 256, 0, stream>>>(XR, LNB, ln_g, ln_b, pc, pc + 4096, ALPHA, BETA,
                                        nullptr, nullptr, nullptr, nullptr);
    gemm_kernel<<<dim3(448, 2), 256, 0, stream>>>(LNB, cWi, cbi, 1, nullptr, QB, nullptr, nullptr);
    gemm_kernel<<<dim3(448, 4), 256, 0, stream>>>(LNA, cWi + 128 * 128, cbi + 128, 2, nullptr,
                                                  nullptr, KB, VB);
    if (l < 5) {
      attn_kernel<<<dim3(8, 128), 448, 0, stream>>>(QB, KB, VB, ALPHA, BETA, GAMMA, DELTA, OB);
      gemm_kernel<<<dim3(448, 2), 256, 0, stream>>>(OB, cWo, cbo, 4, XL, nullptr, nullptr, nullptr);
    }
    // l == 5: attention output / xl update are dead; corresp reads QB/KB + tables.
  }
  corresp_kernel<<<dim3(128, 2), 448, 0, stream>>>(QB, KB, ALPHA, BETA, GAMMA, DELTA,
                                                   (float*)d_out);
}

// Round 5
// 1897.988 us; speedup vs baseline: 1.8798x; 1.7489x over previous
//
#include <hip/hip_runtime.h>

typedef unsigned short u16;
typedef unsigned int u32;

#define W_ 224
#define H_ 128
#define C_ 128
#define NH 8
#define HD 16
#define PREP_STRIDE 4128  // 4*8*128 w-tables + 4*8 scalars
#define KSTR 40           // Ksh/Qsh/Pbuf row stride (bf16): 16B-aligned b128 rows, 2-way banks (free)
#define VSTR 232          // Vt row stride (bf16): 16B-aligned, 2-way banks (free)

typedef __bf16 bf16x8 __attribute__((ext_vector_type(8)));
typedef float f32x4 __attribute__((ext_vector_type(4)));

__device__ __forceinline__ u16 f2bf(float f) {
  u32 u = __float_as_uint(f);
  return (u16)((u + 0x7FFFu + ((u >> 16) & 1u)) >> 16);
}
__device__ __forceinline__ float bflo(u32 u) { return __uint_as_float(u << 16); }
__device__ __forceinline__ float bfhi(u32 u) { return __uint_as_float(u & 0xFFFF0000u); }

// ---------------------------------------------------------------------------
// Rank-1 PE decomposition prep (see R1 notes): rpe[d] = (d-223)*(W u) + b,
// collapsed to per-row affine tables, all fp32.
// ---------------------------------------------------------------------------
__global__ __launch_bounds__(256) void prep_kernel(
    const float* __restrict__ self_Wi, const float* __restrict__ self_bi,
    const float* __restrict__ cross_Wi, const float* __restrict__ cross_bi,
    float* __restrict__ prep) {
  __shared__ float u[128];
  __shared__ float A[256];
  const int s = blockIdx.x, l = s >> 1;
  const float* Wi = (s & 1) ? cross_Wi + (size_t)l * 384 * 128 : self_Wi + (size_t)l * 384 * 128;
  const float* bi = (s & 1) ? cross_bi + l * 384 : self_bi + l * 384;
  const int tid = threadIdx.x;
  if (tid < 128) {
    float ex = (float)(tid & ~1) * (1.f / 128.f);
    u[tid] = expf(-ex * logf(10000.f));
  }
  __syncthreads();
  {
    float a = 0.f;
    const float* wr = Wi + (size_t)tid * 128;
    for (int f = 0; f < 128; ++f) a += wr[f] * u[f];
    A[tid] = a;
  }
  __syncthreads();
  float* out = prep + (size_t)s * PREP_STRIDE;
  for (int t = tid; t < 4096; t += 256) {
    int v = t >> 10, e = (t >> 7) & 7, f = t & 127;
    float acc = 0.f;
#pragma unroll
    for (int c = 0; c < 16; ++c) {
      int qrow = e * 16 + c, krow = 128 + e * 16 + c;
      if (v == 0)      acc += Wi[(size_t)qrow * 128 + f] * A[krow];
      else if (v == 1) acc += Wi[(size_t)qrow * 128 + f] * bi[krow];
      else if (v == 2) acc += Wi[(size_t)krow * 128 + f] * A[qrow];
      else             acc += Wi[(size_t)krow * 128 + f] * bi[qrow];
    }
    out[t] = acc * 0.25f;
  }
  if (tid < 32) {
    int v = tid >> 3, e = tid & 7;
    float acc = 0.f;
#pragma unroll
    for (int c = 0; c < 16; ++c) {
      int qrow = e * 16 + c, krow = 128 + e * 16 + c;
      if (v == 0)      acc += bi[qrow] * A[krow];
      else if (v == 1) acc += bi[qrow] * bi[krow];
      else if (v == 2) acc += bi[krow] * A[qrow];
      else             acc += bi[krow] * bi[qrow];
    }
    out[4096 + tid] = acc * 0.25f;
  }
}

// ---------------------------------------------------------------------------
// Generic 64x64-tile bf16 MFMA GEMM:  out = A[M x 128] * B[N x 128]^T + bias
// ---------------------------------------------------------------------------
__global__ __launch_bounds__(256) void gemm_kernel(
    const u16* __restrict__ A, const u16* __restrict__ B,
    const float* __restrict__ bias, int mode, float* __restrict__ fout,
    u16* __restrict__ out0, u16* __restrict__ out1, u16* __restrict__ out2) {
  __shared__ u16 As[64 * 136];
  __shared__ u16 Bs[64 * 136];
  const int tid = threadIdx.x;
  const int M0 = blockIdx.x * 64, N0 = blockIdx.y * 64;
  const uint4* Ag = (const uint4*)(A + (size_t)M0 * 128);
  const uint4* Bg = (const uint4*)(B + (size_t)N0 * 128);
  for (int t = tid; t < 1024; t += 256) {
    int row = t >> 4, cc = t & 15;
    *(uint4*)&As[row * 136 + cc * 8] = Ag[row * 16 + cc];
  }
  for (int t = tid; t < 1024; t += 256) {
    int row = t >> 4, cc = t & 15;
    *(uint4*)&Bs[row * 136 + cc * 8] = Bg[row * 16 + cc];
  }
  __syncthreads();
  const int wave = tid >> 6, lane = tid & 63;
  const int wm = (wave >> 1) * 32, wn = (wave & 1) * 32;
  const int lr = lane & 15, kq = (lane >> 4) * 8;
  f32x4 acc[2][2] = {};
#pragma unroll
  for (int ks = 0; ks < 4; ++ks) {
    int ko = ks * 32 + kq;
    bf16x8 a0 = *(const bf16x8*)&As[(wm + lr) * 136 + ko];
    bf16x8 a1 = *(const bf16x8*)&As[(wm + 16 + lr) * 136 + ko];
    bf16x8 b0 = *(const bf16x8*)&Bs[(wn + lr) * 136 + ko];
    bf16x8 b1 = *(const bf16x8*)&Bs[(wn + 16 + lr) * 136 + ko];
    acc[0][0] = __builtin_amdgcn_mfma_f32_16x16x32_bf16(a0, b0, acc[0][0], 0, 0, 0);
    acc[0][1] = __builtin_amdgcn_mfma_f32_16x16x32_bf16(a0, b1, acc[0][1], 0, 0, 0);
    acc[1][0] = __builtin_amdgcn_mfma_f32_16x16x32_bf16(a1, b0, acc[1][0], 0, 0, 0);
    acc[1][1] = __builtin_amdgcn_mfma_f32_16x16x32_bf16(a1, b1, acc[1][1], 0, 0, 0);
  }
  const int colq = lane & 15, rowq = (lane >> 4) * 4;
#pragma unroll
  for (int tm = 0; tm < 2; ++tm)
#pragma unroll
    for (int tn = 0; tn < 2; ++tn) {
#pragma unroll
      for (int r = 0; r < 4; ++r) {
        int row = M0 + wm + tm * 16 + rowq + r;
        int col = N0 + wn + tn * 16 + colq;
        float v = acc[tm][tn][r] + bias[col];
        if (mode == 4) {
          fout[(size_t)row * 128 + col] += v;
        } else if (mode == 5) {
          fout[(size_t)row * 128 + col] = v;
        } else {
          int part = (mode == 0) ? (col >> 7) : ((mode == 1) ? 0 : 1 + (col >> 7));
          int cc = col & 127;
          int e = cc >> 4, c = cc & 15;
          int b = row & 127, pos = row >> 7;
          size_t off = ((size_t)(b * NH + e) * W_ + pos) * HD + c;
          if (part == 0)
            out0[off] = f2bf(v * 0.25f);
          else if (part == 1)
            out1[off] = f2bf(v);
          else
            out2[off] = f2bf(v);
        }
      }
    }
}

// ---------------------------------------------------------------------------
// MFMA flash attention per (head e, batch-row b). 448 threads = 7 waves,
// each wave owns 2 Q-tiles of 16 rows. Per 32-j super-tile:
//   S^T = K·Q^T via 2x mfma_f32_16x16x32_bf16 (K-dim 16..31 zero-padded);
//   the PE affine term rides in 6 of the padded contraction slots.
//   Softmax state (m, lsum, p) is per-lane for COLUMN i=li (S^T C-layout);
//   the O accumulator (PV C-layout) holds ROWS i=g*4+r — so the online
//   rescale factor must be shuffled from lane g*4+r (R4 bug: used sc for
//   column li directly -> wrong-row rescale).
// ---------------------------------------------------------------------------
__global__ __launch_bounds__(448) void attn_kernel(
    const u16* __restrict__ qb, const u16* __restrict__ kb,
    const u16* __restrict__ vb, const float* __restrict__ ALPHA,
    const float* __restrict__ BETA, const float* __restrict__ GAMMA,
    const float* __restrict__ DELTA, u16* __restrict__ obuf) {
  __shared__ u16 Ksh[224 * KSTR];
  __shared__ u16 Qsh[224 * KSTR];
  __shared__ u16 Vt[16 * VSTR];
  __shared__ u16 Pbuf[7][16 * KSTR];
  const int e = blockIdx.x, b = blockIdx.y;
  const size_t hb = (size_t)(b * NH + e);
  const int tid = threadIdx.x;
  const u32 ONE = 0x3F80u;

  if (tid < 224) {
    const int j = tid;
    const uint4* src = (const uint4*)(kb + (hb * W_ + j) * HD);
    uint4 a = src[0], b2 = src[1];
    *(uint4*)&Ksh[j * KSTR] = a;
    *(uint4*)&Ksh[j * KSTR + 8] = b2;
    float G = GAMMA[hb * 224 + j];
    float D = DELTA[hb * 224 + j];
    float jf = (float)j;
    float P = G * jf + D;
    u16 Phi = f2bf(P);
    float Plo = P - __uint_as_float((u32)Phi << 16);
    u32* ex = (u32*)&Ksh[j * KSTR + 16];
    ex[0] = (u32)f2bf(G) | ((u32)Phi << 16);
    ex[1] = (u32)f2bf(Plo) | ((u32)f2bf(jf) << 16);
    ex[2] = ONE | (ONE << 16);
#pragma unroll
    for (int z = 3; z < 12; ++z) ex[z] = 0;
    const uint4* vsrc = (const uint4*)(vb + (hb * W_ + j) * HD);
    uint4 va = vsrc[0], vb4 = vsrc[1];
    u32 w[8] = {va.x, va.y, va.z, va.w, vb4.x, vb4.y, vb4.z, vb4.w};
#pragma unroll
    for (int c = 0; c < 16; ++c)
      Vt[c * VSTR + j] = (c & 1) ? (u16)(w[c >> 1] >> 16) : (u16)(w[c >> 1] & 0xFFFF);
  } else {
    const int i = tid - 224;
    const uint4* src = (const uint4*)(qb + (hb * W_ + i) * HD);
    uint4 a = src[0], b2 = src[1];
    *(uint4*)&Qsh[i * KSTR] = a;
    *(uint4*)&Qsh[i * KSTR + 8] = b2;
    float al = ALPHA[hb * 224 + i];
    float be = BETA[hb * 224 + i];
    float ifl = (float)i;
    float Q = be - al * ifl;
    u16 Qhi = f2bf(Q);
    float Qlo = Q - __uint_as_float((u32)Qhi << 16);
    u32* ex = (u32*)&Qsh[i * KSTR + 16];
    ex[0] = (u32)f2bf(-ifl) | (ONE << 16);
    ex[1] = ONE | ((u32)f2bf(al) << 16);
    ex[2] = (u32)Qhi | ((u32)f2bf(Qlo) << 16);
#pragma unroll
    for (int z = 3; z < 12; ++z) ex[z] = 0;
  }
  __syncthreads();

  const int wid = tid >> 6, lane = tid & 63;
  const int g = lane >> 4, li = lane & 15;
  u16* pb = &Pbuf[wid][0];

  for (int qt = wid * 2; qt < wid * 2 + 2; ++qt) {
    const int i0 = qt * 16;
    const bf16x8 Bq = *(const bf16x8*)&Qsh[(i0 + li) * KSTR + g * 8];
    f32x4 O = {0.f, 0.f, 0.f, 0.f};
    float m = -1e30f, lsum = 0.f;
#pragma unroll 1
    for (int js = 0; js < 7; ++js) {
      const int j0 = js * 32;
      const bf16x8 A0 = *(const bf16x8*)&Ksh[(j0 + li) * KSTR + g * 8];
      const bf16x8 A1 = *(const bf16x8*)&Ksh[(j0 + 16 + li) * KSTR + g * 8];
      const f32x4 Z = {0.f, 0.f, 0.f, 0.f};
      f32x4 C0 = __builtin_amdgcn_mfma_f32_16x16x32_bf16(A0, Bq, Z, 0, 0, 0);
      f32x4 C1 = __builtin_amdgcn_mfma_f32_16x16x32_bf16(A1, Bq, Z, 0, 0, 0);
      float cand = fmaxf(fmaxf(fmaxf(C0[0], C0[1]), fmaxf(C0[2], C0[3])),
                         fmaxf(fmaxf(C1[0], C1[1]), fmaxf(C1[2], C1[3])));
      cand = fmaxf(cand, __shfl_xor(cand, 16));
      cand = fmaxf(cand, __shfl_xor(cand, 32));
      const float mn = fmaxf(m, cand);
      const float sc = __expf(m - mn);  // rescale for COLUMN i = i0+li
      m = mn;
      // O rows are i = i0+g*4+r -> fetch each row's scale from lane g*4+r
      O[0] *= __shfl(sc, g * 4 + 0);
      O[1] *= __shfl(sc, g * 4 + 1);
      O[2] *= __shfl(sc, g * 4 + 2);
      O[3] *= __shfl(sc, g * 4 + 3);
      lsum *= sc;
      float p0 = __expf(C0[0] - m), p1 = __expf(C0[1] - m);
      float p2 = __expf(C0[2] - m), p3 = __expf(C0[3] - m);
      float p4 = __expf(C1[0] - m), p5 = __expf(C1[1] - m);
      float p6 = __expf(C1[2] - m), p7 = __expf(C1[3] - m);
      float ps = ((p0 + p1) + (p2 + p3)) + ((p4 + p5) + (p6 + p7));
      ps += __shfl_xor(ps, 16);
      ps += __shfl_xor(ps, 32);
      lsum += ps;
      // P (C-layout: row j, col i=li) -> LDS in [i][j32] order
      u16* pr = pb + li * KSTR + g * 4;
      pr[0] = f2bf(p0); pr[1] = f2bf(p1); pr[2] = f2bf(p2); pr[3] = f2bf(p3);
      pr[16] = f2bf(p4); pr[17] = f2bf(p5); pr[18] = f2bf(p6); pr[19] = f2bf(p7);
      const bf16x8 Ap = *(const bf16x8*)&Pbuf[wid][li * KSTR + g * 8];
      const bf16x8 Bv = *(const bf16x8*)&Vt[li * VSTR + j0 + g * 8];
      O = __builtin_amdgcn_mfma_f32_16x16x32_bf16(Ap, Bv, O, 0, 0, 0);
    }
#pragma unroll
    for (int r = 0; r < 4; ++r) {
      const float lr = __shfl(lsum, g * 4 + r);
      const int irow = i0 + g * 4 + r;
      obuf[((size_t)irow * H_ + b) * C_ + e * HD + li] = f2bf(O[r] * (1.f / lr));
    }
  }
}

// ---------------------------------------------------------------------------
// LayerNorm over C=128 fused with the fp32 affine-PE table GEMVs.
// ---------------------------------------------------------------------------
__global__ __launch_bounds__(256) void ln_kernel(
    float* __restrict__ x, u16* __restrict__ xbf, const float* __restrict__ g,
    const float* __restrict__ b, const float* __restrict__ wq,
    const float* __restrict__ cq, float* __restrict__ outA, float* __restrict__ outB,
    const float* __restrict__ wk, const float* __restrict__ ck,
    float* __restrict__ outG, float* __restrict__ outD) {
  __shared__ float ys[4][128];
  __shared__ float ws[32][129];
  const int tid = threadIdx.x;
  if (wq)
    for (int t = tid; t < 2048; t += 256) ws[t >> 7][t & 127] = wq[t];
  if (wk)
    for (int t = tid; t < 2048; t += 256) ws[16 + (t >> 7)][t & 127] = wk[t];
  const int row = blockIdx.x * 4 + (tid >> 6);
  const int lane = tid & 63;
  float2* xp = (float2*)(x + (size_t)row * 128);
  float2 v = xp[lane];
  float s1 = v.x + v.y, s2 = v.x * v.x + v.y * v.y;
#pragma unroll
  for (int k = 1; k < 64; k <<= 1) {
    s1 += __shfl_xor(s1, k);
    s2 += __shfl_xor(s2, k);
  }
  float mean = s1 * (1.f / 128.f);
  float var = s2 * (1.f / 128.f) - mean * mean;
  float rstd = rsqrtf(var + 1e-5f);
  float2 gg = ((const float2*)g)[lane];
  float2 bb = ((const float2*)b)[lane];
  float y0 = (v.x - mean) * rstd * gg.x + bb.x;
  float y1 = (v.y - mean) * rstd * gg.y + bb.y;
  float2 w2;
  w2.x = y0;
  w2.y = y1;
  xp[lane] = w2;
  ((u32*)xbf)[(size_t)row * 64 + lane] = (u32)f2bf(y0) | ((u32)f2bf(y1) << 16);
  ys[tid >> 6][2 * lane] = y0;
  ys[tid >> 6][2 * lane + 1] = y1;
  __syncthreads();
  if (tid < 128) {
    const int r = tid >> 5, o = tid & 31;
    const int side = o >> 4, oo = o & 15;
    const bool active = side ? (wk != nullptr) : (wq != nullptr);
    if (active) {
      const float* wrow = ws[side * 16 + oo];
      const float* yr = ys[r];
      float a0 = 0.f, a1 = 0.f, a2 = 0.f, a3 = 0.f;
#pragma unroll 4
      for (int f = 0; f < 128; f += 4) {
        a0 += yr[f] * wrow[f];
        a1 += yr[f + 1] * wrow[f + 1];
        a2 += yr[f + 2] * wrow[f + 2];
        a3 += yr[f + 3] * wrow[f + 3];
      }
      float acc = (a0 + a1) + (a2 + a3);
      int p = blockIdx.x * 4 + r;
      int i = p >> 7, bb2 = p & 127;
      int val = oo >> 3, e = oo & 7;
      float c = side ? ck[val * 8 + e] : cq[val * 8 + e];
      float* dst = side ? (val ? outD : outG) : (val ? outB : outA);
      dst[((size_t)(bb2 * 8 + e)) * 224 + i] = acc + c;
    }
  }
}

// Gather x[b][c][h][w] -> bf16 A-matrix rows p = w*128 + h*2 + b, cols c.
__global__ __launch_bounds__(256) void transpose_kernel(const float* __restrict__ x,
                                                        u16* __restrict__ xT) {
  __shared__ float tile[128][57];
  const int wt = blockIdx.x * 56, hi = blockIdx.y, bi = blockIdx.z;
  const int wave = threadIdx.x >> 6, lane = threadIdx.x & 63;
  for (int c = wave; c < 128; c += 4) {
    if (lane < 56)
      tile[c][lane] = x[(((size_t)bi * 128 + c) * 64 + hi) * 224 + wt + lane];
  }
  __syncthreads();
  u32* dst = (u32*)xT;
  for (int w = wave; w < 56; w += 4) {
    int p = (wt + w) * 128 + hi * 2 + bi;
    float a = tile[lane * 2][w], b2 = tile[lane * 2 + 1][w];
    dst[(size_t)p * 64 + lane] = (u32)f2bf(a) | ((u32)f2bf(b2) << 16);
  }
}

// ---------------------------------------------------------------------------
// Final soft-argmax over recomputed layer-5 cross logits.
// ---------------------------------------------------------------------------
__global__ __launch_bounds__(448) void corresp_kernel(
    const u16* __restrict__ qb, const u16* __restrict__ kb,
    const float* __restrict__ ALPHA, const float* __restrict__ BETA,
    const float* __restrict__ GAMMA, const float* __restrict__ DELTA,
    float* __restrict__ out) {
  __shared__ __align__(16) u32 Ks[224 * 68];  // stride 68 dwords (272B, 16B-aligned)
  __shared__ float Gs[224], Ds[224];
  const int b = blockIdx.x, tid = threadIdx.x;
  const u32* kg = (const u32*)kb;
  for (int t = tid; t < 224 * 64; t += 448) {
    int row = t >> 6, col = t & 63;
    Ks[row * 68 + col] = kg[((size_t)(b * 8 + (col >> 3)) * 224 + row) * 8 + (col & 7)];
  }
  if (tid < 224) {
    float gs = 0.f, ds = 0.f;
#pragma unroll
    for (int e = 0; e < 8; ++e) {
      gs += GAMMA[((size_t)(b * 8 + e)) * 224 + tid];
      ds += DELTA[((size_t)(b * 8 + e)) * 224 + tid];
    }
    Gs[tid] = gs;
    Ds[tid] = ds;
  }
  __syncthreads();
  const int ii = tid >> 2, jq = tid & 3;
  const int i = blockIdx.y * 112 + ii;
  float qf[128];
  const u32* qg = (const u32*)qb;
#pragma unroll
  for (int uu = 0; uu < 64; ++uu) {
    u32 qv = qg[((size_t)(b * 8 + (uu >> 3)) * 224 + i) * 8 + (uu & 7)];
    qf[2 * uu] = bflo(qv);
    qf[2 * uu + 1] = bfhi(qv);
  }
  float ai = 0.f, bi_ = 0.f;
#pragma unroll
  for (int e = 0; e < 8; ++e) {
    ai += ALPHA[((size_t)(b * 8 + e)) * 224 + i];
    bi_ += BETA[((size_t)(b * 8 + e)) * 224 + i];
  }
  float m = -1e30f, l = 0.f, wj = 0.f;
  for (int jj = 0; jj < 56; ++jj) {
    int jo = jj + jq * 14;
    if (jo >= 56) jo -= 56;
    const int j = jq * 56 + jo;
    const u32* kr = &Ks[j * 68];
    float p0 = 0.f, p1 = 0.f, p2 = 0.f, p3 = 0.f;
#pragma unroll
    for (int w = 0; w < 16; ++w) {
      uint4 kk = *(const uint4*)&kr[w * 4];
      p0 += qf[w * 8 + 0] * bflo(kk.x) + qf[w * 8 + 1] * bfhi(kk.x);
      p1 += qf[w * 8 + 2] * bflo(kk.y) + qf[w * 8 + 3] * bfhi(kk.y);
      p2 += qf[w * 8 + 4] * bflo(kk.z) + qf[w * 8 + 5] * bfhi(kk.z);
      p3 += qf[w * 8 + 6] * bflo(kk.w) + qf[w * 8 + 7] * bfhi(kk.w);
    }
    float s = (p0 + p1) + (p2 + p3);
    s += (float)(j - i) * (ai + Gs[j]) + bi_ + Ds[j];
    if (s > m) {
      float fs = __expf(m - s);
      l *= fs;
      wj *= fs;
      m = s;
    }
    float p = __expf(s - m);
    l += p;
    wj += p * (float)j;
  }
#pragma unroll
  for (int r = 1; r <= 2; r <<= 1) {
    float mo = __shfl_xor(m, r);
    float m2 = fmaxf(m, mo);
    float fa = __expf(m - m2), fb = __expf(mo - m2);
    l = l * fa + __shfl_xor(l, r) * fb;
    wj = wj * fa + __shfl_xor(wj, r) * fb;
    m = m2;
  }
  if (jq == 0) out[(size_t)b * 224 + i] = (float)i - wj / fmaxf(l, 1e-30f);
}

__global__ __launch_bounds__(256) void cvt_kernel(const float* __restrict__ src,
                                                  u16* __restrict__ dst, int n) {
  int idx = blockIdx.x * 256 + threadIdx.x;
  if (idx < n) dst[idx] = f2bf(src[idx]);
}

extern "C" void kernel_launch(void* const* d_in, const int* in_sizes, int n_in,
                              void* d_out, int out_size, void* d_ws, size_t ws_size,
                              hipStream_t stream) {
  (void)in_sizes; (void)n_in; (void)out_size; (void)ws_size;
  const float* x_l = (const float*)d_in[0];
  const float* x_r = (const float*)d_in[1];
  const float* feat_w = (const float*)d_in[2];
  const float* feat_b = (const float*)d_in[3];
  const float* self_Wi = (const float*)d_in[4];
  const float* self_bi = (const float*)d_in[5];
  const float* self_Wo = (const float*)d_in[6];
  const float* self_bo = (const float*)d_in[7];
  const float* cross_Wi = (const float*)d_in[8];
  const float* cross_bi = (const float*)d_in[9];
  const float* cross_Wo = (const float*)d_in[10];
  const float* cross_bo = (const float*)d_in[11];
  const float* ln_g = (const float*)d_in[12];
  const float* ln_b = (const float*)d_in[13];

  char* ws = (char*)d_ws;
  size_t off = 0;
  auto alloc = [&](size_t bytes) {
    char* p = ws + off;
    off += (bytes + 255) & ~(size_t)255;
    return p;
  };
  float* XL = (float*)alloc((size_t)W_ * H_ * C_ * 4);
  float* XR = (float*)alloc((size_t)W_ * H_ * C_ * 4);
  u16* LNA = (u16*)alloc((size_t)W_ * H_ * C_ * 2);
  u16* LNB = (u16*)alloc((size_t)W_ * H_ * C_ * 2);
  u16* XT = (u16*)alloc((size_t)W_ * H_ * C_ * 2);
  u16* QB = (u16*)alloc((size_t)H_ * NH * W_ * HD * 2);
  u16* KB = (u16*)alloc((size_t)H_ * NH * W_ * HD * 2);
  u16* VB = (u16*)alloc((size_t)H_ * NH * W_ * HD * 2);
  u16* OB = (u16*)alloc((size_t)W_ * H_ * C_ * 2);
  u16* WSWI = (u16*)alloc((size_t)6 * 384 * 128 * 2);
  u16* WSWO = (u16*)alloc((size_t)6 * 128 * 128 * 2);
  u16* WCWI = (u16*)alloc((size_t)6 * 384 * 128 * 2);
  u16* WCWO = (u16*)alloc((size_t)6 * 128 * 128 * 2);
  u16* WFEAT = (u16*)alloc((size_t)128 * 128 * 2);
  float* PREP = (float*)alloc((size_t)12 * PREP_STRIDE * 4);
  float* ALPHA = (float*)alloc((size_t)H_ * NH * W_ * 4);
  float* BETA = (float*)alloc((size_t)H_ * NH * W_ * 4);
  float* GAMMA = (float*)alloc((size_t)H_ * NH * W_ * 4);
  float* DELTA = (float*)alloc((size_t)H_ * NH * W_ * 4);

  cvt_kernel<<<64, 256, 0, stream>>>(feat_w, WFEAT, 16384);
  cvt_kernel<<<1152, 256, 0, stream>>>(self_Wi, WSWI, 294912);
  cvt_kernel<<<384, 256, 0, stream>>>(self_Wo, WSWO, 98304);
  cvt_kernel<<<1152, 256, 0, stream>>>(cross_Wi, WCWI, 294912);
  cvt_kernel<<<384, 256, 0, stream>>>(cross_Wo, WCWO, 98304);
  prep_kernel<<<12, 256, 0, stream>>>(self_Wi, self_bi, cross_Wi, cross_bi, PREP);

  transpose_kernel<<<dim3(4, 64, 2), 256, 0, stream>>>(x_l, XT);
  gemm_kernel<<<dim3(448, 2), 256, 0, stream>>>(XT, WFEAT, feat_b, 5, XL, nullptr, nullptr, nullptr);
  transpose_kernel<<<dim3(4, 64, 2), 256, 0, stream>>>(x_r, XT);
  gemm_kernel<<<dim3(448, 2), 256, 0, stream>>>(XT, WFEAT, feat_b, 5, XR, nullptr, nullptr, nullptr);

  for (int l = 0; l < 6; ++l) {
    const u16* sWi = WSWI + (size_t)l * 384 * 128;
    const u16* sWo = WSWO + (size_t)l * 128 * 128;
    const u16* cWi = WCWI + (size_t)l * 384 * 128;
    const u16* cWo = WCWO + (size_t)l * 128 * 128;
    const float* sbi = self_bi + l * 384;
    const float* sbo = self_bo + l * 128;
    const float* cbi = cross_bi + l * 384;
    const float* cbo = cross_bo + l * 128;
    const float* ps = PREP + (size_t)(l * 2) * PREP_STRIDE;
    const float* pc = PREP + (size_t)(l * 2 + 1) * PREP_STRIDE;

    // --- self attention on xl ---
    ln_kernel<<<7168, 256, 0, stream>>>(XL, LNA, ln_g, ln_b, ps, ps + 4096, ALPHA, BETA,
                                        ps + 2048, ps + 4112, GAMMA, DELTA);
    gemm_kernel<<<dim3(448, 6), 256, 0, stream>>>(LNA, sWi, sbi, 0, nullptr, QB, KB, VB);
    attn_kernel<<<dim3(8, 128), 448, 0, stream>>>(QB, KB, VB, ALPHA, BETA, GAMMA, DELTA, OB);
    gemm_kernel<<<dim3(448, 2), 256, 0, stream>>>(OB, sWo, sbo, 4, XL, nullptr, nullptr, nullptr);

    // --- self attention on xr ---
    ln_kernel<<<7168, 256, 0, stream>>>(XR, LNA, ln_g, ln_b, ps, ps + 4096, ALPHA, BETA,
                                        ps + 2048, ps + 4112, GAMMA, DELTA);
    gemm_kernel<<<dim3(448, 6), 256, 0, stream>>>(LNA, sWi, sbi, 0, nullptr, QB, KB, VB);
    attn_kernel<<<dim3(8, 128), 448, 0, stream>>>(QB, KB, VB, ALPHA, BETA, GAMMA, DELTA, OB);
    gemm_kernel<<<dim3(448, 2), 256, 0, stream>>>(OB, sWo, sbo, 4, XR, nullptr, nullptr, nullptr);

    // --- cross attention: q from LN(xr), k/v from LN(xl); xl += out ---
    ln_kernel<<<7168, 256, 0, stream>>>(XL, LNA, ln_g, ln_b, nullptr, nullptr, nullptr, nullptr,
                                        pc + 2048, pc + 4112, GAMMA, DELTA);
    ln_kernel<<<7168, 256, 0, stream>>>(XR, LNB, ln_g, ln_b, pc, pc + 4096, ALPHA, BETA,
                                        nullptr, nullptr, nullptr, nullptr);
    gemm_kernel<<<dim3(448, 2), 256, 0, stream>>>(LNB, cWi, cbi, 1, nullptr, QB, nullptr, nullptr);
    gemm_kernel<<<dim3(448, 4), 256, 0, stream>>>(LNA, cWi + 128 * 128, cbi + 128, 2, nullptr,
                                                  nullptr, KB, VB);
    if (l < 5) {
      attn_kernel<<<dim3(8, 128), 448, 0, stream>>>(QB, KB, VB, ALPHA, BETA, GAMMA, DELTA, OB);
      gemm_kernel<<<dim3(448, 2), 256, 0, stream>>>(OB, cWo, cbo, 4, XL, nullptr, nullptr, nullptr);
    }
    // l == 5: attention output / xl update are dead; corresp reads QB/KB + tables.
  }
  corresp_kernel<<<dim3(128, 2), 448, 0, stream>>>(QB, KB, ALPHA, BETA, GAMMA, DELTA,
                                                   (float*)d_out);
}

// Round 6
// 1688.034 us; speedup vs baseline: 2.1136x; 1.1244x over previous
//
#include <hip/hip_runtime.h>

typedef unsigned short u16;
typedef unsigned int u32;

#define W_ 224
#define H_ 128
#define C_ 128
#define NH 8
#define HD 16
#define ROWS_ (W_ * H_)          // 28672 rows per image
#define PREP_STRIDE 4128
#define KSTR 40
#define VSTR 232

typedef __bf16 bf16x8 __attribute__((ext_vector_type(8)));
typedef float f32x4 __attribute__((ext_vector_type(4)));

__device__ __forceinline__ u16 f2bf(float f) {
  u32 u = __float_as_uint(f);
  return (u16)((u + 0x7FFFu + ((u >> 16) & 1u)) >> 16);
}
__device__ __forceinline__ float bflo(u32 u) { return __uint_as_float(u << 16); }
__device__ __forceinline__ float bfhi(u32 u) { return __uint_as_float(u & 0xFFFF0000u); }

// ---------------------------------------------------------------------------
// Rank-1 PE decomposition prep: rpe[d] = (d-223)*(W u) + b -> per-row affine.
// ---------------------------------------------------------------------------
__global__ __launch_bounds__(256) void prep_kernel(
    const float* __restrict__ self_Wi, const float* __restrict__ self_bi,
    const float* __restrict__ cross_Wi, const float* __restrict__ cross_bi,
    float* __restrict__ prep) {
  __shared__ float u[128];
  __shared__ float A[256];
  const int s = blockIdx.x, l = s >> 1;
  const float* Wi = (s & 1) ? cross_Wi + (size_t)l * 384 * 128 : self_Wi + (size_t)l * 384 * 128;
  const float* bi = (s & 1) ? cross_bi + l * 384 : self_bi + l * 384;
  const int tid = threadIdx.x;
  if (tid < 128) {
    float ex = (float)(tid & ~1) * (1.f / 128.f);
    u[tid] = expf(-ex * logf(10000.f));
  }
  __syncthreads();
  {
    float a = 0.f;
    const float* wr = Wi + (size_t)tid * 128;
    for (int f = 0; f < 128; ++f) a += wr[f] * u[f];
    A[tid] = a;
  }
  __syncthreads();
  float* out = prep + (size_t)s * PREP_STRIDE;
  for (int t = tid; t < 4096; t += 256) {
    int v = t >> 10, e = (t >> 7) & 7, f = t & 127;
    float acc = 0.f;
#pragma unroll
    for (int c = 0; c < 16; ++c) {
      int qrow = e * 16 + c, krow = 128 + e * 16 + c;
      if (v == 0)      acc += Wi[(size_t)qrow * 128 + f] * A[krow];
      else if (v == 1) acc += Wi[(size_t)qrow * 128 + f] * bi[krow];
      else if (v == 2) acc += Wi[(size_t)krow * 128 + f] * A[qrow];
      else             acc += Wi[(size_t)krow * 128 + f] * bi[qrow];
    }
    out[t] = acc * 0.25f;
  }
  if (tid < 32) {
    int v = tid >> 3, e = tid & 7;
    float acc = 0.f;
#pragma unroll
    for (int c = 0; c < 16; ++c) {
      int qrow = e * 16 + c, krow = 128 + e * 16 + c;
      if (v == 0)      acc += bi[qrow] * A[krow];
      else if (v == 1) acc += bi[qrow] * bi[krow];
      else if (v == 2) acc += bi[krow] * A[qrow];
      else             acc += bi[krow] * bi[qrow];
    }
    out[4096 + tid] = acc * 0.25f;
  }
}

// ---------------------------------------------------------------------------
// Generic 64x64-tile bf16 MFMA GEMM:  out = A[M x 128] * B[N x 128]^T + bias
// mode 0: scatter q/k/v, merged xl+xr rows (row>=28672 -> b+=128)
// mode 1: scatter q only (cross), rows<28672
// mode 2: scatter k/v (cross)
// mode 4: fout += acc + bias  (out-proj residual)
// mode 5: fout  = acc + bias  (feat conv)
// ---------------------------------------------------------------------------
__global__ __launch_bounds__(256) void gemm_kernel(
    const u16* __restrict__ A, const u16* __restrict__ B,
    const float* __restrict__ bias, int mode, float* __restrict__ fout,
    u16* __restrict__ out0, u16* __restrict__ out1, u16* __restrict__ out2) {
  __shared__ u16 As[64 * 136];
  __shared__ u16 Bs[64 * 136];
  const int tid = threadIdx.x;
  const int M0 = blockIdx.x * 64, N0 = blockIdx.y * 64;
  const uint4* Ag = (const uint4*)(A + (size_t)M0 * 128);
  const uint4* Bg = (const uint4*)(B + (size_t)N0 * 128);
  for (int t = tid; t < 1024; t += 256) {
    int row = t >> 4, cc = t & 15;
    *(uint4*)&As[row * 136 + cc * 8] = Ag[row * 16 + cc];
  }
  for (int t = tid; t < 1024; t += 256) {
    int row = t >> 4, cc = t & 15;
    *(uint4*)&Bs[row * 136 + cc * 8] = Bg[row * 16 + cc];
  }
  __syncthreads();
  const int wave = tid >> 6, lane = tid & 63;
  const int wm = (wave >> 1) * 32, wn = (wave & 1) * 32;
  const int lr = lane & 15, kq = (lane >> 4) * 8;
  f32x4 acc[2][2] = {};
#pragma unroll
  for (int ks = 0; ks < 4; ++ks) {
    int ko = ks * 32 + kq;
    bf16x8 a0 = *(const bf16x8*)&As[(wm + lr) * 136 + ko];
    bf16x8 a1 = *(const bf16x8*)&As[(wm + 16 + lr) * 136 + ko];
    bf16x8 b0 = *(const bf16x8*)&Bs[(wn + lr) * 136 + ko];
    bf16x8 b1 = *(const bf16x8*)&Bs[(wn + 16 + lr) * 136 + ko];
    acc[0][0] = __builtin_amdgcn_mfma_f32_16x16x32_bf16(a0, b0, acc[0][0], 0, 0, 0);
    acc[0][1] = __builtin_amdgcn_mfma_f32_16x16x32_bf16(a0, b1, acc[0][1], 0, 0, 0);
    acc[1][0] = __builtin_amdgcn_mfma_f32_16x16x32_bf16(a1, b0, acc[1][0], 0, 0, 0);
    acc[1][1] = __builtin_amdgcn_mfma_f32_16x16x32_bf16(a1, b1, acc[1][1], 0, 0, 0);
  }
  const int colq = lane & 15, rowq = (lane >> 4) * 4;
#pragma unroll
  for (int tm = 0; tm < 2; ++tm)
#pragma unroll
    for (int tn = 0; tn < 2; ++tn) {
#pragma unroll
      for (int r = 0; r < 4; ++r) {
        int row = M0 + wm + tm * 16 + rowq + r;
        int col = N0 + wn + tn * 16 + colq;
        float v = acc[tm][tn][r] + bias[col];
        if (mode == 4) {
          fout[(size_t)row * 128 + col] += v;
        } else if (mode == 5) {
          fout[(size_t)row * 128 + col] = v;
        } else {
          int part = (mode == 0) ? (col >> 7) : ((mode == 1) ? 0 : 1 + (col >> 7));
          int cc = col & 127;
          int e = cc >> 4, c = cc & 15;
          int rloc = row, badd = 0;
          if (mode == 0 && row >= ROWS_) { rloc = row - ROWS_; badd = 128; }
          int b = (rloc & 127) + badd, pos = rloc >> 7;
          size_t off = ((size_t)(b * NH + e) * W_ + pos) * HD + c;
          if (part == 0)
            out0[off] = f2bf(v * 0.25f);
          else if (part == 1)
            out1[off] = f2bf(v);
          else
            out2[off] = f2bf(v);
        }
      }
    }
}

// ---------------------------------------------------------------------------
// MFMA flash attention per (head e, batch-row b), b in [0, gridDim.y).
// Two-pass softmax: pass A = 14 pipelined MFMAs (S^T strip in 56 VGPRs) +
// exact column max (fmax scan + 2 shfls); pass B = exp/accumulate + PV MFMA.
// PE affine term rides in 6 zero-padded contraction slots (see R4 notes).
// ---------------------------------------------------------------------------
__global__ __launch_bounds__(448) void attn_kernel(
    const u16* __restrict__ qb, const u16* __restrict__ kb,
    const u16* __restrict__ vb, const float* __restrict__ ALPHA,
    const float* __restrict__ BETA, const float* __restrict__ GAMMA,
    const float* __restrict__ DELTA, u16* __restrict__ obuf) {
  __shared__ u16 Ksh[224 * KSTR];
  __shared__ u16 Qsh[224 * KSTR];
  __shared__ u16 Vt[16 * VSTR];
  __shared__ u16 Pbuf[7][16 * KSTR];
  const int e = blockIdx.x, b = blockIdx.y;
  const size_t hb = (size_t)(b * NH + e);
  const int tid = threadIdx.x;
  const u32 ONE = 0x3F80u;

  if (tid < 224) {
    const int j = tid;
    const uint4* src = (const uint4*)(kb + (hb * W_ + j) * HD);
    uint4 a = src[0], b2 = src[1];
    *(uint4*)&Ksh[j * KSTR] = a;
    *(uint4*)&Ksh[j * KSTR + 8] = b2;
    float G = GAMMA[hb * 224 + j];
    float D = DELTA[hb * 224 + j];
    float jf = (float)j;
    float P = G * jf + D;
    u16 Phi = f2bf(P);
    float Plo = P - __uint_as_float((u32)Phi << 16);
    u32* ex = (u32*)&Ksh[j * KSTR + 16];
    ex[0] = (u32)f2bf(G) | ((u32)Phi << 16);
    ex[1] = (u32)f2bf(Plo) | ((u32)f2bf(jf) << 16);
    ex[2] = ONE | (ONE << 16);
#pragma unroll
    for (int z = 3; z < 12; ++z) ex[z] = 0;
    const uint4* vsrc = (const uint4*)(vb + (hb * W_ + j) * HD);
    uint4 va = vsrc[0], vb4 = vsrc[1];
    u32 w[8] = {va.x, va.y, va.z, va.w, vb4.x, vb4.y, vb4.z, vb4.w};
#pragma unroll
    for (int c = 0; c < 16; ++c)
      Vt[c * VSTR + j] = (c & 1) ? (u16)(w[c >> 1] >> 16) : (u16)(w[c >> 1] & 0xFFFF);
  } else {
    const int i = tid - 224;
    const uint4* src = (const uint4*)(qb + (hb * W_ + i) * HD);
    uint4 a = src[0], b2 = src[1];
    *(uint4*)&Qsh[i * KSTR] = a;
    *(uint4*)&Qsh[i * KSTR + 8] = b2;
    float al = ALPHA[hb * 224 + i];
    float be = BETA[hb * 224 + i];
    float ifl = (float)i;
    float Q = be - al * ifl;
    u16 Qhi = f2bf(Q);
    float Qlo = Q - __uint_as_float((u32)Qhi << 16);
    u32* ex = (u32*)&Qsh[i * KSTR + 16];
    ex[0] = (u32)f2bf(-ifl) | (ONE << 16);
    ex[1] = ONE | ((u32)f2bf(al) << 16);
    ex[2] = (u32)Qhi | ((u32)f2bf(Qlo) << 16);
#pragma unroll
    for (int z = 3; z < 12; ++z) ex[z] = 0;
  }
  __syncthreads();

  const int wid = tid >> 6, lane = tid & 63;
  const int g = lane >> 4, li = lane & 15;
  u16* pb = &Pbuf[wid][0];
  const int obase = (b & 128) ? ROWS_ : 0;
  const int blow = b & 127;

  for (int qt = wid * 2; qt < wid * 2 + 2; ++qt) {
    const int i0 = qt * 16;
    const bf16x8 Bq = *(const bf16x8*)&Qsh[(i0 + li) * KSTR + g * 8];
    f32x4 C[7][2];
    // --- pass A: full S^T strip, back-to-back MFMAs ---
#pragma unroll
    for (int js = 0; js < 7; ++js) {
      const bf16x8 A0 = *(const bf16x8*)&Ksh[(js * 32 + li) * KSTR + g * 8];
      const bf16x8 A1 = *(const bf16x8*)&Ksh[(js * 32 + 16 + li) * KSTR + g * 8];
      const f32x4 Z = {0.f, 0.f, 0.f, 0.f};
      C[js][0] = __builtin_amdgcn_mfma_f32_16x16x32_bf16(A0, Bq, Z, 0, 0, 0);
      C[js][1] = __builtin_amdgcn_mfma_f32_16x16x32_bf16(A1, Bq, Z, 0, 0, 0);
    }
    float m = -1e30f;
#pragma unroll
    for (int js = 0; js < 7; ++js)
#pragma unroll
      for (int h = 0; h < 2; ++h)
        m = fmaxf(m, fmaxf(fmaxf(C[js][h][0], C[js][h][1]), fmaxf(C[js][h][2], C[js][h][3])));
    m = fmaxf(m, __shfl_xor(m, 16));
    m = fmaxf(m, __shfl_xor(m, 32));
    // --- pass B: exp, P->LDS relayout, PV MFMA ---
    f32x4 O = {0.f, 0.f, 0.f, 0.f};
    float lsum = 0.f;
#pragma unroll
    for (int js = 0; js < 7; ++js) {
      float p0 = __expf(C[js][0][0] - m), p1 = __expf(C[js][0][1] - m);
      float p2 = __expf(C[js][0][2] - m), p3 = __expf(C[js][0][3] - m);
      float p4 = __expf(C[js][1][0] - m), p5 = __expf(C[js][1][1] - m);
      float p6 = __expf(C[js][1][2] - m), p7 = __expf(C[js][1][3] - m);
      lsum += ((p0 + p1) + (p2 + p3)) + ((p4 + p5) + (p6 + p7));
      u16* pr = pb + li * KSTR + g * 4;
      pr[0] = f2bf(p0); pr[1] = f2bf(p1); pr[2] = f2bf(p2); pr[3] = f2bf(p3);
      pr[16] = f2bf(p4); pr[17] = f2bf(p5); pr[18] = f2bf(p6); pr[19] = f2bf(p7);
      const bf16x8 Ap = *(const bf16x8*)&Pbuf[wid][li * KSTR + g * 8];
      const bf16x8 Bv = *(const bf16x8*)&Vt[li * VSTR + js * 32 + g * 8];
      O = __builtin_amdgcn_mfma_f32_16x16x32_bf16(Ap, Bv, O, 0, 0, 0);
    }
    lsum += __shfl_xor(lsum, 16);
    lsum += __shfl_xor(lsum, 32);
#pragma unroll
    for (int r = 0; r < 4; ++r) {
      const float lr = __shfl(lsum, g * 4 + r);
      const int irow = i0 + g * 4 + r;
      obuf[((size_t)(obase + irow * 128 + blow)) * C_ + e * HD + li] = f2bf(O[r] * (1.f / lr));
    }
  }
}

// ---------------------------------------------------------------------------
// LayerNorm over C=128 fused with affine-PE GEMVs. Grid covers xl+xr (57344
// rows). mode 0 (self): both table sides, b_out = half*128 + blow.
// mode 1 (cross): XL half -> k-side only, XR half -> q-side only, b_out=blow.
// ---------------------------------------------------------------------------
__global__ __launch_bounds__(256) void ln_kernel(
    float* __restrict__ x, u16* __restrict__ xbf, const float* __restrict__ g,
    const float* __restrict__ b, const float* __restrict__ wq,
    const float* __restrict__ cq, float* __restrict__ outA, float* __restrict__ outB,
    const float* __restrict__ wk, const float* __restrict__ ck,
    float* __restrict__ outG, float* __restrict__ outD, int mode) {
  __shared__ float ys[4][128];
  __shared__ float ws[32][129];
  const int tid = threadIdx.x;
  for (int t = tid; t < 2048; t += 256) ws[t >> 7][t & 127] = wq[t];
  for (int t = tid; t < 2048; t += 256) ws[16 + (t >> 7)][t & 127] = wk[t];
  const int row = blockIdx.x * 4 + (tid >> 6);
  const int lane = tid & 63;
  float2* xp = (float2*)(x + (size_t)row * 128);
  float2 v = xp[lane];
  float s1 = v.x + v.y, s2 = v.x * v.x + v.y * v.y;
#pragma unroll
  for (int k = 1; k < 64; k <<= 1) {
    s1 += __shfl_xor(s1, k);
    s2 += __shfl_xor(s2, k);
  }
  float mean = s1 * (1.f / 128.f);
  float var = s2 * (1.f / 128.f) - mean * mean;
  float rstd = rsqrtf(var + 1e-5f);
  float2 gg = ((const float2*)g)[lane];
  float2 bb = ((const float2*)b)[lane];
  float y0 = (v.x - mean) * rstd * gg.x + bb.x;
  float y1 = (v.y - mean) * rstd * gg.y + bb.y;
  float2 w2;
  w2.x = y0;
  w2.y = y1;
  xp[lane] = w2;
  ((u32*)xbf)[(size_t)row * 64 + lane] = (u32)f2bf(y0) | ((u32)f2bf(y1) << 16);
  ys[tid >> 6][2 * lane] = y0;
  ys[tid >> 6][2 * lane + 1] = y1;
  __syncthreads();
  if (tid < 128) {
    const int r = tid >> 5, o = tid & 31;
    const int side = o >> 4, oo = o & 15;
    const int p = blockIdx.x * 4 + r;
    const int half = (p >= ROWS_) ? 1 : 0;
    const int ploc = p - half * ROWS_;
    // mode1: XR(half=1) -> q-side (side 0); XL(half=0) -> k-side (side 1)
    const bool active = (mode == 0) || (half ? (side == 0) : (side == 1));
    if (active) {
      const float* wrow = ws[side * 16 + oo];
      const float* yr = ys[r];
      float a0 = 0.f, a1 = 0.f, a2 = 0.f, a3 = 0.f;
#pragma unroll 4
      for (int f = 0; f < 128; f += 4) {
        a0 += yr[f] * wrow[f];
        a1 += yr[f + 1] * wrow[f + 1];
        a2 += yr[f + 2] * wrow[f + 2];
        a3 += yr[f + 3] * wrow[f + 3];
      }
      float acc = (a0 + a1) + (a2 + a3);
      int i = ploc >> 7, blow = ploc & 127;
      int b_out = (mode == 0) ? half * 128 + blow : blow;
      int val = oo >> 3, e = oo & 7;
      float c = side ? ck[val * 8 + e] : cq[val * 8 + e];
      float* dst = side ? (val ? outD : outG) : (val ? outB : outA);
      dst[((size_t)(b_out * 8 + e)) * 224 + i] = acc + c;
    }
  }
}

// Gather x_l/x_r[b][c][h][w] -> bf16 rows p = img*28672 + w*128 + h*2 + b.
__global__ __launch_bounds__(256) void transpose_kernel(const float* __restrict__ x_l,
                                                        const float* __restrict__ x_r,
                                                        u16* __restrict__ xT) {
  __shared__ float tile[128][57];
  const int wt = blockIdx.x * 56, hi = blockIdx.y;
  const int img = blockIdx.z >> 1, bi = blockIdx.z & 1;
  const float* x = img ? x_r : x_l;
  const int wave = threadIdx.x >> 6, lane = threadIdx.x & 63;
  for (int c = wave; c < 128; c += 4) {
    if (lane < 56)
      tile[c][lane] = x[(((size_t)bi * 128 + c) * 64 + hi) * 224 + wt + lane];
  }
  __syncthreads();
  u32* dst = (u32*)xT;
  for (int w = wave; w < 56; w += 4) {
    int p = img * ROWS_ + (wt + w) * 128 + hi * 2 + bi;
    float a = tile[lane * 2][w], b2 = tile[lane * 2 + 1][w];
    dst[(size_t)p * 64 + lane] = (u32)f2bf(a) | ((u32)f2bf(b2) << 16);
  }
}

// ---------------------------------------------------------------------------
// Final soft-argmax over recomputed layer-5 cross logits.
// ---------------------------------------------------------------------------
__global__ __launch_bounds__(448) void corresp_kernel(
    const u16* __restrict__ qb, const u16* __restrict__ kb,
    const float* __restrict__ ALPHA, const float* __restrict__ BETA,
    const float* __restrict__ GAMMA, const float* __restrict__ DELTA,
    float* __restrict__ out) {
  __shared__ __align__(16) u32 Ks[224 * 68];
  __shared__ float Gs[224], Ds[224];
  const int b = blockIdx.x, tid = threadIdx.x;
  const u32* kg = (const u32*)kb;
  for (int t = tid; t < 224 * 64; t += 448) {
    int row = t >> 6, col = t & 63;
    Ks[row * 68 + col] = kg[((size_t)(b * 8 + (col >> 3)) * 224 + row) * 8 + (col & 7)];
  }
  if (tid < 224) {
    float gs = 0.f, ds = 0.f;
#pragma unroll
    for (int e = 0; e < 8; ++e) {
      gs += GAMMA[((size_t)(b * 8 + e)) * 224 + tid];
      ds += DELTA[((size_t)(b * 8 + e)) * 224 + tid];
    }
    Gs[tid] = gs;
    Ds[tid] = ds;
  }
  __syncthreads();
  const int ii = tid >> 2, jq = tid & 3;
  const int i = blockIdx.y * 112 + ii;
  float qf[128];
  const u32* qg = (const u32*)qb;
#pragma unroll
  for (int uu = 0; uu < 64; ++uu) {
    u32 qv = qg[((size_t)(b * 8 + (uu >> 3)) * 224 + i) * 8 + (uu & 7)];
    qf[2 * uu] = bflo(qv);
    qf[2 * uu + 1] = bfhi(qv);
  }
  float ai = 0.f, bi_ = 0.f;
#pragma unroll
  for (int e = 0; e < 8; ++e) {
    ai += ALPHA[((size_t)(b * 8 + e)) * 224 + i];
    bi_ += BETA[((size_t)(b * 8 + e)) * 224 + i];
  }
  float m = -1e30f, l = 0.f, wj = 0.f;
  for (int jj = 0; jj < 56; ++jj) {
    int jo = jj + jq * 14;
    if (jo >= 56) jo -= 56;
    const int j = jq * 56 + jo;
    const u32* kr = &Ks[j * 68];
    float p0 = 0.f, p1 = 0.f, p2 = 0.f, p3 = 0.f;
#pragma unroll
    for (int w = 0; w < 16; ++w) {
      uint4 kk = *(const uint4*)&kr[w * 4];
      p0 += qf[w * 8 + 0] * bflo(kk.x) + qf[w * 8 + 1] * bfhi(kk.x);
      p1 += qf[w * 8 + 2] * bflo(kk.y) + qf[w * 8 + 3] * bfhi(kk.y);
      p2 += qf[w * 8 + 4] * bflo(kk.z) + qf[w * 8 + 5] * bfhi(kk.z);
      p3 += qf[w * 8 + 6] * bflo(kk.w) + qf[w * 8 + 7] * bfhi(kk.w);
    }
    float s = (p0 + p1) + (p2 + p3);
    s += (float)(j - i) * (ai + Gs[j]) + bi_ + Ds[j];
    if (s > m) {
      float fs = __expf(m - s);
      l *= fs;
      wj *= fs;
      m = s;
    }
    float p = __expf(s - m);
    l += p;
    wj += p * (float)j;
  }
#pragma unroll
  for (int r = 1; r <= 2; r <<= 1) {
    float mo = __shfl_xor(m, r);
    float m2 = fmaxf(m, mo);
    float fa = __expf(m - m2), fb = __expf(mo - m2);
    l = l * fa + __shfl_xor(l, r) * fb;
    wj = wj * fa + __shfl_xor(wj, r) * fb;
    m = m2;
  }
  if (jq == 0) out[(size_t)b * 224 + i] = (float)i - wj / fmaxf(l, 1e-30f);
}

// Single-launch conversion of all five weight tensors to one bf16 buffer.
#define OFF_FEAT 0
#define OFF_SWI 16384
#define OFF_SWO 311296
#define OFF_CWI 409600
#define OFF_CWO 704512
#define N_WALL 802816
__global__ __launch_bounds__(256) void cvt_all_kernel(
    const float* __restrict__ feat_w, const float* __restrict__ self_Wi,
    const float* __restrict__ self_Wo, const float* __restrict__ cross_Wi,
    const float* __restrict__ cross_Wo, u16* __restrict__ dst) {
  int idx = blockIdx.x * 256 + threadIdx.x;
  if (idx >= N_WALL) return;
  float v;
  if (idx < OFF_SWI)       v = feat_w[idx];
  else if (idx < OFF_SWO)  v = self_Wi[idx - OFF_SWI];
  else if (idx < OFF_CWI)  v = self_Wo[idx - OFF_SWO];
  else if (idx < OFF_CWO)  v = cross_Wi[idx - OFF_CWI];
  else                     v = cross_Wo[idx - OFF_CWO];
  dst[idx] = f2bf(v);
}

extern "C" void kernel_launch(void* const* d_in, const int* in_sizes, int n_in,
                              void* d_out, int out_size, void* d_ws, size_t ws_size,
                              hipStream_t stream) {
  (void)in_sizes; (void)n_in; (void)out_size; (void)ws_size;
  const float* x_l = (const float*)d_in[0];
  const float* x_r = (const float*)d_in[1];
  const float* feat_w = (const float*)d_in[2];
  const float* feat_b = (const float*)d_in[3];
  const float* self_Wi = (const float*)d_in[4];
  const float* self_bi = (const float*)d_in[5];
  const float* self_Wo = (const float*)d_in[6];
  const float* self_bo = (const float*)d_in[7];
  const float* cross_Wi = (const float*)d_in[8];
  const float* cross_bi = (const float*)d_in[9];
  const float* cross_Wo = (const float*)d_in[10];
  const float* cross_bo = (const float*)d_in[11];
  const float* ln_g = (const float*)d_in[12];
  const float* ln_b = (const float*)d_in[13];

  char* ws = (char*)d_ws;
  size_t off = 0;
  auto alloc = [&](size_t bytes) {
    char* p = ws + off;
    off += (bytes + 255) & ~(size_t)255;
    return p;
  };
  float* XL = (float*)alloc((size_t)2 * ROWS_ * C_ * 4);   // xl+xr contiguous
  u16* LNB = (u16*)alloc((size_t)2 * ROWS_ * C_ * 2);      // merged LN bf16
  u16* QB = (u16*)alloc((size_t)256 * NH * W_ * HD * 2);   // also XT scratch
  u16* KB = (u16*)alloc((size_t)256 * NH * W_ * HD * 2);
  u16* VB = (u16*)alloc((size_t)256 * NH * W_ * HD * 2);
  u16* OB = (u16*)alloc((size_t)2 * ROWS_ * C_ * 2);
  u16* WALL = (u16*)alloc((size_t)N_WALL * 2);
  float* PREP = (float*)alloc((size_t)12 * PREP_STRIDE * 4);
  float* ALPHA = (float*)alloc((size_t)256 * NH * W_ * 4);
  float* BETA = (float*)alloc((size_t)256 * NH * W_ * 4);
  float* GAMMA = (float*)alloc((size_t)256 * NH * W_ * 4);
  float* DELTA = (float*)alloc((size_t)256 * NH * W_ * 4);

  cvt_all_kernel<<<3136, 256, 0, stream>>>(feat_w, self_Wi, self_Wo, cross_Wi, cross_Wo, WALL);
  prep_kernel<<<12, 256, 0, stream>>>(self_Wi, self_bi, cross_Wi, cross_bi, PREP);

  // feature conv: both images in one transpose + one gemm (XT aliases QB)
  transpose_kernel<<<dim3(4, 64, 4), 256, 0, stream>>>(x_l, x_r, QB);
  gemm_kernel<<<dim3(896, 2), 256, 0, stream>>>(QB, WALL + OFF_FEAT, feat_b, 5, XL,
                                                nullptr, nullptr, nullptr);

  for (int l = 0; l < 6; ++l) {
    const u16* sWi = WALL + OFF_SWI + (size_t)l * 384 * 128;
    const u16* sWo = WALL + OFF_SWO + (size_t)l * 128 * 128;
    const u16* cWi = WALL + OFF_CWI + (size_t)l * 384 * 128;
    const u16* cWo = WALL + OFF_CWO + (size_t)l * 128 * 128;
    const float* sbi = self_bi + l * 384;
    const float* sbo = self_bo + l * 128;
    const float* cbi = cross_bi + l * 384;
    const float* cbo = cross_bo + l * 128;
    const float* ps = PREP + (size_t)(l * 2) * PREP_STRIDE;
    const float* pc = PREP + (size_t)(l * 2 + 1) * PREP_STRIDE;

    // --- self attention on xl AND xr, batched (shared weights) ---
    ln_kernel<<<14336, 256, 0, stream>>>(XL, LNB, ln_g, ln_b, ps, ps + 4096, ALPHA, BETA,
                                         ps + 2048, ps + 4112, GAMMA, DELTA, 0);
    gemm_kernel<<<dim3(896, 6), 256, 0, stream>>>(LNB, sWi, sbi, 0, nullptr, QB, KB, VB);
    attn_kernel<<<dim3(8, 256), 448, 0, stream>>>(QB, KB, VB, ALPHA, BETA, GAMMA, DELTA, OB);
    gemm_kernel<<<dim3(896, 2), 256, 0, stream>>>(OB, sWo, sbo, 4, XL, nullptr, nullptr, nullptr);

    // --- cross attention: q from LN(xr), k/v from LN(xl); xl += out ---
    ln_kernel<<<14336, 256, 0, stream>>>(XL, LNB, ln_g, ln_b, pc, pc + 4096, ALPHA, BETA,
                                         pc + 2048, pc + 4112, GAMMA, DELTA, 1);
    gemm_kernel<<<dim3(448, 2), 256, 0, stream>>>(LNB + (size_t)ROWS_ * C_, cWi, cbi, 1,
                                                  nullptr, QB, nullptr, nullptr);
    gemm_kernel<<<dim3(448, 4), 256, 0, stream>>>(LNB, cWi + 128 * 128, cbi + 128, 2, nullptr,
                                                  nullptr, KB, VB);
    if (l < 5) {
      attn_kernel<<<dim3(8, 128), 448, 0, stream>>>(QB, KB, VB, ALPHA, BETA, GAMMA, DELTA, OB);
      gemm_kernel<<<dim3(448, 2), 256, 0, stream>>>(OB, cWo, cbo, 4, XL, nullptr, nullptr, nullptr);
    }
    // l == 5: attention output / xl update are dead; corresp reads QB/KB + tables.
  }
  corresp_kernel<<<dim3(128, 2), 448, 0, stream>>>(QB, KB, ALPHA, BETA, GAMMA, DELTA,
                                                   (float*)d_out);
}